// Round 8
// baseline (219.047 us; speedup 1.0000x reference)
//
#include <hip/hip_runtime.h>
#include <hip/hip_bf16.h>
#include <math.h>

// B=2, S=2048, D=1024, H=16, dk=64.
// split(fp32->bf16 hi/lo) -> MFMA split-GEMM (3-term) with fused RoPE / V-transpose
// epilogues (k/v written PRE-TILED chunk-major for conflict-free attn LDS)
// -> 32x32-MFMA flash attention (64 q per wave, register softmax, no max-tracking,
//    no P-LDS) -> MFMA split-GEMM -> out.
//
// Tiled K layout per (b,h): tile t (64 keys) at t*4096 elems; within tile:
//   elem(key r, dk d) at chunk(d>>3)*512 + r*8 + (d&7).   (chunk = 1024B of 64 rows)
// Tiled V layout per (b,h): tile t (64 keys) at t*4096; elem(dk dkr, key s):
//   chunk((s&63)>>3)*512 + dkr*8 + (s&7).
//
// ws (64 MB), liveness-reused:
//  [0,8)   QAh -> VAh -> Xh     [8,16)  QAl -> VAl -> Xl
//  [16,24) qb (bf16 B,H,S,dk)
//  [24,32) KAh -> vt (bf16 tiled)
//  [32,40) KAl
//  [40,48) kb (bf16 tiled)
//  [48,64) W splits (hi/lo per weight)

#define B_ 2
#define S_ 2048
#define D_ 1024
#define H_ 16
#define DK 64

typedef __attribute__((ext_vector_type(8)))  __bf16 bf16x8;
typedef __attribute__((ext_vector_type(4)))  float  f32x4;
typedef __attribute__((ext_vector_type(16))) float  f32x16;
typedef __attribute__((ext_vector_type(8)))  unsigned short u16x8;
typedef __attribute__((ext_vector_type(4)))  unsigned short u16x4;

#if __has_builtin(__builtin_amdgcn_exp2f)
#define EXP2(x) __builtin_amdgcn_exp2f(x)
#else
#define EXP2(x) exp2f(x)
#endif

static __device__ __forceinline__ unsigned short f2bf(float x) {
    union { float f; unsigned u; } v; v.f = x;
    unsigned r = v.u + 0x7FFFu + ((v.u >> 16) & 1u);   // RNE
    return (unsigned short)(r >> 16);
}
static __device__ __forceinline__ float bf2f(unsigned short h) {
    union { unsigned u; float f; } v; v.u = ((unsigned)h) << 16;
    return v.f;
}
static __device__ __forceinline__ unsigned cvtpk(float lo, float hi) {
    unsigned r;
    asm("v_cvt_pk_bf16_f32 %0, %1, %2" : "=v"(r) : "v"(lo), "v"(hi));
    return r;
}
static __device__ __forceinline__ void gload_lds16(const void* g, void* l) {
    __builtin_amdgcn_global_load_lds(
        (const __attribute__((address_space(1))) void*)g,
        (__attribute__((address_space(3))) void*)l, 16, 0, 0);
}

// ---------------------------------------------------------------------------
// fp32 -> bf16 hi/lo split (Dekker).
// ---------------------------------------------------------------------------
__global__ __launch_bounds__(256) void asplit(const float* __restrict__ in,
                                              unsigned short* __restrict__ hi,
                                              unsigned short* __restrict__ lo)
{
    const size_t e = ((size_t)blockIdx.x * 256 + threadIdx.x) * 8;
    float4 a = *(const float4*)(in + e);
    float4 b = *(const float4*)(in + e + 4);
    float x[8] = {a.x,a.y,a.z,a.w,b.x,b.y,b.z,b.w};
    u16x8 h, l;
    #pragma unroll
    for (int j = 0; j < 8; ++j) {
        unsigned short hb = f2bf(x[j]);
        h[j] = hb;
        l[j] = f2bf(x[j] - bf2f(hb));
    }
    *(u16x8*)(hi + e) = h;
    *(u16x8*)(lo + e) = l;
}

__global__ __launch_bounds__(256) void wsplit4(
    const float* __restrict__ W0, const float* __restrict__ W1,
    const float* __restrict__ W2, const float* __restrict__ W3,
    unsigned short* __restrict__ out)
{
    const int idx = blockIdx.x * 256 + threadIdx.x;
    const int t = idx >> 17;
    const size_t e = (size_t)(idx & 131071) * 8;
    const float* src = (t==0 ? W0 : t==1 ? W1 : t==2 ? W2 : W3) + e;
    unsigned short* hi = out + (size_t)t * 2097152 + e;
    unsigned short* lo = hi + 1048576;
    float4 a = *(const float4*)src;
    float4 b = *(const float4*)(src + 4);
    float x[8] = {a.x,a.y,a.z,a.w,b.x,b.y,b.z,b.w};
    u16x8 h, l;
    #pragma unroll
    for (int j = 0; j < 8; ++j) {
        unsigned short hb = f2bf(x[j]);
        h[j] = hb;
        l[j] = f2bf(x[j] - bf2f(hb));
    }
    *(u16x8*)hi = h;
    *(u16x8*)lo = l;
}

// ---------------------------------------------------------------------------
// Split-bf16 MFMA GEMM. MODE 0: fp32 out. MODE 1: RoPE*QSC -> qb (B,H,S,dk).
// MODE 2: RoPE -> kb TILED. MODE 3: +bias -> vt TILED.
// ---------------------------------------------------------------------------
template <int MODE>
__global__ __launch_bounds__(512) void mfma_gemm(
    const unsigned short* __restrict__ Ah, const unsigned short* __restrict__ Al,
    const unsigned short* __restrict__ Wh, const unsigned short* __restrict__ Wl,
    const float* __restrict__ bias, void* __restrict__ OutP)
{
    __shared__ unsigned short lds[2][4][4096];
    const int tid = threadIdx.x;
    const int w = tid >> 6, lane = tid & 63;
    const int l15 = lane & 15, g4 = lane >> 4;
    const int wr = w >> 1, wc = w & 1;
    const int bx = blockIdx.x, by = blockIdx.y;

    const int tileId = w >> 1;
    const int halfT  = w & 1;
    const unsigned short* gsrc = (tileId==0) ? Ah : (tileId==1) ? Al : (tileId==2) ? Wh : Wl;
    const int row0 = (tileId < 2) ? bx * 128 : by * 128;
    const int r_l = lane >> 2, c_l = lane & 3;
    const int cs = c_l ^ (r_l & 3);
    const char* gp0 = (const char*)gsrc + (size_t)(row0 + halfT*64 + r_l) * 2048 + cs * 16;

    f32x4 acc[2][4];
    #pragma unroll
    for (int m = 0; m < 2; ++m)
        #pragma unroll
        for (int n = 0; n < 4; ++n) acc[m][n] = (f32x4){0.f,0.f,0.f,0.f};

    #define STAGE(T, BUF) do {                                              \
        const char* g_ = gp0 + (size_t)(T) * 64;                            \
        unsigned short* lb_ = &lds[BUF][tileId][halfT * 2048];              \
        gload_lds16(g_,          lb_);                                      \
        gload_lds16(g_ + 32768,  lb_ + 512);                                \
        gload_lds16(g_ + 65536,  lb_ + 1024);                               \
        gload_lds16(g_ + 98304,  lb_ + 1536);                               \
    } while (0)

    STAGE(0, 0);
    __syncthreads();

    for (int t = 0; t < 32; ++t) {
        const int cur = t & 1;
        if (t < 31) STAGE(t + 1, cur ^ 1);
        const unsigned short* lA_h = lds[cur][0];
        const unsigned short* lA_l = lds[cur][1];
        const unsigned short* lW_h = lds[cur][2];
        const unsigned short* lW_l = lds[cur][3];
        bf16x8 ah[2], al2[2], wh4[4], wl4[4];
        #pragma unroll
        for (int m = 0; m < 2; ++m) {
            const int R = wr*32 + m*16 + l15;
            const int off = R*32 + ((g4 ^ (R & 3)) << 3);
            ah[m]  = *(const bf16x8*)(lA_h + off);
            al2[m] = *(const bf16x8*)(lA_l + off);
        }
        #pragma unroll
        for (int n = 0; n < 4; ++n) {
            const int R = wc*64 + n*16 + l15;
            const int off = R*32 + ((g4 ^ (R & 3)) << 3);
            wh4[n] = *(const bf16x8*)(lW_h + off);
            wl4[n] = *(const bf16x8*)(lW_l + off);
        }
        #pragma unroll
        for (int m = 0; m < 2; ++m)
            #pragma unroll
            for (int n = 0; n < 4; ++n) {
                acc[m][n] = __builtin_amdgcn_mfma_f32_16x16x32_bf16(ah[m],  wh4[n], acc[m][n], 0,0,0);
                acc[m][n] = __builtin_amdgcn_mfma_f32_16x16x32_bf16(ah[m],  wl4[n], acc[m][n], 0,0,0);
                acc[m][n] = __builtin_amdgcn_mfma_f32_16x16x32_bf16(al2[m], wh4[n], acc[m][n], 0,0,0);
            }
        __syncthreads();
    }
    #undef STAGE

    const int colBase = by*128 + wc*64;
    const int rowBase = bx*128 + wr*32;

    if constexpr (MODE == 0) {
        float* Out = (float*)OutP;
        #pragma unroll
        for (int m = 0; m < 2; ++m) {
            const int row = rowBase + m*16 + g4*4;
            #pragma unroll
            for (int n = 0; n < 4; ++n) {
                const int col = colBase + n*16 + l15;
                const float bb = bias[col];
                #pragma unroll
                for (int r = 0; r < 4; ++r)
                    Out[(size_t)(row + r) * 1024 + col] = acc[m][n][r] + bb;
            }
        }
    } else if constexpr (MODE == 1 || MODE == 2) {
        unsigned short* Out = (unsigned short*)OutP;
        const int h = colBase >> 6;
        const float QSC = (MODE == 1) ? 0.125f * 1.44269504088896340736f : 1.0f;
        #pragma unroll
        for (int m = 0; m < 2; ++m) {
            const int srow0 = rowBase + m*16 + g4*4;
            const int b = srow0 >> 11;
            unsigned short* hb2 = Out + (size_t)(b*H_ + h) * S_ * DK;
            #pragma unroll
            for (int n = 0; n < 2; ++n) {
                const int d = n*16 + l15;                       // 0..31
                const float invf = exp2f((float)d * -0.4152410118609203f);
                const float b1 = bias[h*64 + d], b2 = bias[h*64 + d + 32];
                #pragma unroll
                for (int r = 0; r < 4; ++r) {
                    const int s = (srow0 + r) & 2047;
                    const float x1 = acc[m][n][r]   + b1;
                    const float x2 = acc[m][n+2][r] + b2;
                    float sn, cc;
                    __sincosf((float)s * invf, &sn, &cc);
                    const float o1 = (x1*cc - x2*sn) * QSC;
                    const float o2 = (x2*cc + x1*sn) * QSC;
                    if (MODE == 1) {
                        unsigned short* dst = hb2 + (size_t)s * DK;
                        dst[d]      = f2bf(o1);
                        dst[d + 32] = f2bf(o2);
                    } else {
                        unsigned short* tb = hb2 + (s >> 6) * 4096 + (s & 63) * 8;
                        tb[(d >> 3) * 512 + (d & 7)]        = f2bf(o1);
                        tb[(d >> 3) * 512 + 2048 + (d & 7)] = f2bf(o2);
                    }
                }
            }
        }
    } else {   // MODE 3: vt TILED
        unsigned short* Out = (unsigned short*)OutP;
        const int h = colBase >> 6;
        #pragma unroll
        for (int m = 0; m < 2; ++m) {
            const int srow0 = rowBase + m*16 + g4*4;
            const int b = srow0 >> 11, s0 = srow0 & 2047;
            unsigned short* tb = Out + (size_t)(b*H_ + h) * S_ * DK
                               + (s0 >> 6) * 4096 + ((s0 & 63) >> 3) * 512 + (s0 & 7);
            #pragma unroll
            for (int n = 0; n < 4; ++n) {
                const int d = n*16 + l15;
                const float bb = bias[h*64 + d];
                u16x4 pk;
                #pragma unroll
                for (int r = 0; r < 4; ++r) pk[r] = f2bf(acc[m][n][r] + bb);
                *(u16x4*)(tb + d * 8) = pk;
            }
        }
    }
}

// ---------------------------------------------------------------------------
// 32x32-MFMA flash attention, 64 q per wave (2 q-subtiles): each K/V fragment
// ds_read feeds TWO mfmas -> LDS pipe per MFMA halved vs round 7.
// Register softmax, no max tracking (bounded scores). Pre-tiled K/V staging
// (identity memcpy, 0 bank conflicts). 4 waves x 64 q = 256 q/block; grid 256
// (1 block/CU); XCD-grouped bh (4 bh per XCD, KV L2-resident).
// ---------------------------------------------------------------------------
__global__ __launch_bounds__(256, 1) void attn_mfma5(
    const unsigned short* __restrict__ Qb, const unsigned short* __restrict__ Kb,
    const unsigned short* __restrict__ Vt,
    unsigned short* __restrict__ Xh, unsigned short* __restrict__ Xl)
{
    __shared__ __align__(16) char lds[32768];    // 2 bufs x (K 8K | V 8K)
    const unsigned bid = blockIdx.x;             // 256 blocks
    const int xcd = bid & 7, idx = bid >> 3;     // idx 0..31
    const int bh  = xcd * 4 + (idx >> 3);        // 4 bh per XCD
    const int qt  = idx & 7;                     // 8 q-tiles of 256
    const int tid = threadIdx.x;
    const int w = tid >> 6, lane = tid & 63;
    const int l31 = lane & 31, hi = lane >> 5;
    const size_t bhO = (size_t)bh * S_ * DK;
    const int q0 = qt * 256 + w * 64;

    // staging role: waves 0,1 copy K chunks; waves 2,3 copy V chunks.
    const unsigned short* sbase = ((w < 2) ? Kb : Vt) + bhO;
    const int ch0 = (w & 1) * 4;
    const int dof = ((w < 2) ? 0 : 8192) + ch0 * 1024;

    // Q B-fragments: [sub][ks], col=q = q0+sub*32+l31, k = ks*16 + hi*8 + j
    bf16x8 qf[2][4];
    #pragma unroll
    for (int sub = 0; sub < 2; ++sub)
        #pragma unroll
        for (int ks = 0; ks < 4; ++ks)
            qf[sub][ks] = *(const bf16x8*)(Qb + bhO + (size_t)(q0 + sub*32 + l31) * DK + ks*16 + hi*8);

    f32x16 oT[2][2];
    #pragma unroll
    for (int sub = 0; sub < 2; ++sub)
        #pragma unroll
        for (int dh = 0; dh < 2; ++dh)
            #pragma unroll
            for (int r = 0; r < 16; ++r) oT[sub][dh][r] = 0.f;
    float l0 = 0.f, l1 = 0.f;   // lane-local half-sums per subtile

    #define ASTAGE(T, BUF) do {                                                   \
        const unsigned short* g_ = sbase + (size_t)(T) * 4096 + ch0 * 512 + lane * 8; \
        char* d_ = lds + (BUF) * 16384 + dof;                                     \
        gload_lds16(g_,        d_);                                               \
        gload_lds16(g_ + 512,  d_ + 1024);                                        \
        gload_lds16(g_ + 1024, d_ + 2048);                                        \
        gload_lds16(g_ + 1536, d_ + 3072);                                        \
    } while (0)

    ASTAGE(0, 0);
    __syncthreads();

    for (int t = 0; t < 32; ++t) {
        const int cur = t & 1;
        if (t < 31) ASTAGE(t + 1, cur ^ 1);
        const char* Kl = lds + cur * 16384;
        const char* Vl = Kl + 8192;

        // ---- S^T = K · Q^T : per kb2, K-frag shared by both q-subtiles ----
        f32x16 s2[2][2];
        __builtin_amdgcn_s_setprio(1);
        #pragma unroll
        for (int kb2 = 0; kb2 < 2; ++kb2) {
            f32x16 a0, a1;
            #pragma unroll
            for (int r = 0; r < 16; ++r) { a0[r] = 0.f; a1[r] = 0.f; }
            const int row16 = (kb2 * 32 + l31) * 16;
            #pragma unroll
            for (int ks = 0; ks < 4; ++ks) {
                bf16x8 kf = *(const bf16x8*)(Kl + (ks*2 + hi) * 1024 + row16);
                a0 = __builtin_amdgcn_mfma_f32_32x32x16_bf16(kf, qf[0][ks], a0, 0, 0, 0);
                a1 = __builtin_amdgcn_mfma_f32_32x32x16_bf16(kf, qf[1][ks], a1, 0, 0, 0);
            }
            s2[0][kb2] = a0; s2[1][kb2] = a1;
        }
        __builtin_amdgcn_s_setprio(0);

        // ---- softmax, no max subtraction (bounded scores) ----
        {
            float ls0 = 0.f, ls1 = 0.f;
            #pragma unroll
            for (int kb2 = 0; kb2 < 2; ++kb2)
                #pragma unroll
                for (int r = 0; r < 16; ++r) {
                    const float p0 = EXP2(s2[0][kb2][r]);
                    const float p1 = EXP2(s2[1][kb2][r]);
                    s2[0][kb2][r] = p0; ls0 += p0;
                    s2[1][kb2][r] = p1; ls1 += p1;
                }
            l0 += ls0; l1 += ls1;
        }

        // ---- PV: build P-frags in registers; V-frag shared by both subs ----
        #pragma unroll
        for (int ks2 = 0; ks2 < 4; ++ks2) {
            const int kb2 = ks2 >> 1;
            const int R0  = (ks2 & 1) * 8;
            union { unsigned u[4]; bf16x8 v; } pf[2];
            #pragma unroll
            for (int sub = 0; sub < 2; ++sub) {
                const unsigned pkA0 = cvtpk(s2[sub][kb2][R0+0], s2[sub][kb2][R0+1]);
                const unsigned pkA1 = cvtpk(s2[sub][kb2][R0+2], s2[sub][kb2][R0+3]);
                const unsigned pkB0 = cvtpk(s2[sub][kb2][R0+4], s2[sub][kb2][R0+5]);
                const unsigned pkB1 = cvtpk(s2[sub][kb2][R0+6], s2[sub][kb2][R0+7]);
                const unsigned snd0 = hi ? pkA0 : pkB0;
                const unsigned snd1 = hi ? pkA1 : pkB1;
                const unsigned rcv0 = __shfl_xor(snd0, 32, 64);
                const unsigned rcv1 = __shfl_xor(snd1, 32, 64);
                pf[sub].u[0] = hi ? rcv0 : pkA0;
                pf[sub].u[1] = hi ? rcv1 : pkA1;
                pf[sub].u[2] = hi ? pkB0 : rcv0;
                pf[sub].u[3] = hi ? pkB1 : rcv1;
            }
            __builtin_amdgcn_s_setprio(1);
            #pragma unroll
            for (int dh = 0; dh < 2; ++dh) {
                bf16x8 vf = *(const bf16x8*)(Vl + (ks2*2 + hi) * 1024 + (dh*32 + l31) * 16);
                oT[0][dh] = __builtin_amdgcn_mfma_f32_32x32x16_bf16(vf, pf[0].v, oT[0][dh], 0, 0, 0);
                oT[1][dh] = __builtin_amdgcn_mfma_f32_32x32x16_bf16(vf, pf[1].v, oT[1][dh], 0, 0, 0);
            }
            __builtin_amdgcn_s_setprio(0);
        }
        __syncthreads();
    }
    #undef ASTAGE

    // ---- epilogue: combine l halves, O^T/l -> Xh/Xl bf16 splits ----
    l0 += __shfl_xor(l0, 32, 64);
    l1 += __shfl_xor(l1, 32, 64);
    const int b = bh >> 4, h = bh & 15;
    #pragma unroll
    for (int sub = 0; sub < 2; ++sub) {
        const float inv = 1.0f / (sub ? l1 : l0);
        const int q = q0 + sub*32 + l31;
        unsigned short* xh = Xh + (((size_t)b * S_ + q) * H_ + h) * DK;
        unsigned short* xl = Xl + (((size_t)b * S_ + q) * H_ + h) * DK;
        #pragma unroll
        for (int dh = 0; dh < 2; ++dh)
            #pragma unroll
            for (int tt = 0; tt < 4; ++tt) {
                const int dk0 = dh*32 + tt*8 + hi*4;
                u16x4 hv, lv;
                #pragma unroll
                for (int r = 0; r < 4; ++r) {
                    const float o = oT[sub][dh][tt*4 + r] * inv;
                    const unsigned short hb = f2bf(o);
                    hv[r] = hb;
                    lv[r] = f2bf(o - bf2f(hb));
                }
                *(u16x4*)(xh + dk0) = hv;
                *(u16x4*)(xl + dk0) = lv;
            }
    }
}

// ---------------------------------------------------------------------------
extern "C" void kernel_launch(void* const* d_in, const int* in_sizes, int n_in,
                              void* d_out, int out_size, void* d_ws, size_t ws_size,
                              hipStream_t stream)
{
    const float* query = (const float*)d_in[0];
    const float* key   = (const float*)d_in[1];
    const float* value = (const float*)d_in[2];
    const float* Wq = (const float*)d_in[3];  const float* bq = (const float*)d_in[4];
    const float* Wk = (const float*)d_in[5];  const float* bk = (const float*)d_in[6];
    const float* Wv = (const float*)d_in[7];  const float* bv = (const float*)d_in[8];
    const float* Wo = (const float*)d_in[9];  const float* bo = (const float*)d_in[10];
    float* out = (float*)d_out;

    char* ws = (char*)d_ws;
    const size_t MB = (size_t)1 << 20;
    unsigned short* QAh = (unsigned short*)(ws + 0*MB);
    unsigned short* QAl = (unsigned short*)(ws + 8*MB);
    unsigned short* qb  = (unsigned short*)(ws + 16*MB);
    unsigned short* KAh = (unsigned short*)(ws + 24*MB);
    unsigned short* KAl = (unsigned short*)(ws + 32*MB);
    unsigned short* kb  = (unsigned short*)(ws + 40*MB);
    unsigned short* VAh = (unsigned short*)(ws + 0*MB);
    unsigned short* VAl = (unsigned short*)(ws + 8*MB);
    unsigned short* vt  = (unsigned short*)(ws + 24*MB);
    unsigned short* Xh  = (unsigned short*)(ws + 0*MB);
    unsigned short* Xl  = (unsigned short*)(ws + 8*MB);
    unsigned short* wsp = (unsigned short*)(ws + 48*MB);
    unsigned short* Wqh = wsp;               unsigned short* Wql = wsp + 1048576;
    unsigned short* Wkh = wsp + 2097152;     unsigned short* Wkl = wsp + 3145728;
    unsigned short* Wvh = wsp + 4194304;     unsigned short* Wvl = wsp + 5242880;
    unsigned short* Woh = wsp + 6291456;     unsigned short* Wol = wsp + 7340032;

    dim3 ggrid(32, 8);

    wsplit4<<<2048, 256, 0, stream>>>(Wq, Wk, Wv, Wo, wsp);

    asplit<<<2048, 256, 0, stream>>>(query, QAh, QAl);
    mfma_gemm<1><<<ggrid, 512, 0, stream>>>(QAh, QAl, Wqh, Wql, bq, qb);

    asplit<<<2048, 256, 0, stream>>>(key, KAh, KAl);
    mfma_gemm<2><<<ggrid, 512, 0, stream>>>(KAh, KAl, Wkh, Wkl, bk, kb);

    asplit<<<2048, 256, 0, stream>>>(value, VAh, VAl);
    mfma_gemm<3><<<ggrid, 512, 0, stream>>>(VAh, VAl, Wvh, Wvl, bv, vt);

    attn_mfma5<<<256, 256, 0, stream>>>(qb, kb, vt, Xh, Xl);

    mfma_gemm<0><<<ggrid, 512, 0, stream>>>(Xh, Xl, Woh, Wol, bo, out);
}

// Round 9
// 199.286 us; speedup vs baseline: 1.0992x; 1.0992x over previous
//
#include <hip/hip_runtime.h>
#include <hip/hip_bf16.h>
#include <math.h>

// B=2, S=2048, D=1024, H=16, dk=64.
// splitQW -> MFMA split-GEMMs (fused RoPE / tiled-V epilogues) -> 32x32-MFMA
// flash attention (8-wave block, KVBLK=128, register softmax, no max-tracking)
// -> MFMA split-GEMM -> out.
//
// Tiled K layout per (b,h): 64-key tile t at t*4096 elems; within tile:
//   elem(key r, dk d) at chunk(d>>3)*512 + r*8 + (d&7).
// Tiled V layout per (b,h): 64-key tile t at t*4096; elem(dk dkr, key s):
//   chunk((s&63)>>3)*512 + dkr*8 + (s&7).
//
// ws (64 MB), liveness-reused:
//  [0,8)   QAh -> VAh -> Xh     [8,16)  QAl -> VAl -> Xl
//  [16,24) qb (bf16 B,H,S,dk)
//  [24,32) KAh -> vt (bf16 tiled)
//  [32,40) KAl
//  [40,48) kb (bf16 tiled)
//  [48,64) W splits (hi/lo per weight)

#define B_ 2
#define S_ 2048
#define D_ 1024
#define H_ 16
#define DK 64

typedef __attribute__((ext_vector_type(8)))  __bf16 bf16x8;
typedef __attribute__((ext_vector_type(4)))  float  f32x4;
typedef __attribute__((ext_vector_type(16))) float  f32x16;
typedef __attribute__((ext_vector_type(8)))  unsigned short u16x8;
typedef __attribute__((ext_vector_type(4)))  unsigned short u16x4;

#if __has_builtin(__builtin_amdgcn_exp2f)
#define EXP2(x) __builtin_amdgcn_exp2f(x)
#else
#define EXP2(x) exp2f(x)
#endif

static __device__ __forceinline__ unsigned short f2bf(float x) {
    union { float f; unsigned u; } v; v.f = x;
    unsigned r = v.u + 0x7FFFu + ((v.u >> 16) & 1u);   // RNE
    return (unsigned short)(r >> 16);
}
static __device__ __forceinline__ float bf2f(unsigned short h) {
    union { unsigned u; float f; } v; v.u = ((unsigned)h) << 16;
    return v.f;
}
static __device__ __forceinline__ unsigned cvtpk(float lo, float hi) {
    unsigned r;
    asm("v_cvt_pk_bf16_f32 %0, %1, %2" : "=v"(r) : "v"(lo), "v"(hi));
    return r;
}
static __device__ __forceinline__ void gload_lds16(const void* g, void* l) {
    __builtin_amdgcn_global_load_lds(
        (const __attribute__((address_space(1))) void*)g,
        (__attribute__((address_space(3))) void*)l, 16, 0, 0);
}

static __device__ __forceinline__ void split8(const float* x, u16x8& h, u16x8& l) {
    #pragma unroll
    for (int j = 0; j < 8; ++j) {
        unsigned short hb = f2bf(x[j]);
        h[j] = hb;
        l[j] = f2bf(x[j] - bf2f(hb));
    }
}

// ---------------------------------------------------------------------------
// fp32 -> bf16 hi/lo split (Dekker). 8 elems/thread.
// ---------------------------------------------------------------------------
__global__ __launch_bounds__(256) void asplit(const float* __restrict__ in,
                                              unsigned short* __restrict__ hi,
                                              unsigned short* __restrict__ lo)
{
    const size_t e = ((size_t)blockIdx.x * 256 + threadIdx.x) * 8;
    float4 a = *(const float4*)(in + e);
    float4 b = *(const float4*)(in + e + 4);
    float x[8] = {a.x,a.y,a.z,a.w,b.x,b.y,b.z,b.w};
    u16x8 h, l;
    split8(x, h, l);
    *(u16x8*)(hi + e) = h;
    *(u16x8*)(lo + e) = l;
}

// query split + all 4 weight splits in one launch (saves a dispatch).
// idx < 512K: query elems; else weight t = (idx-512K)>>17.
__global__ __launch_bounds__(256) void splitQW(
    const float* __restrict__ Q,
    const float* __restrict__ W0, const float* __restrict__ W1,
    const float* __restrict__ W2, const float* __restrict__ W3,
    unsigned short* __restrict__ Qh, unsigned short* __restrict__ Ql,
    unsigned short* __restrict__ wout)
{
    const int idx = blockIdx.x * 256 + threadIdx.x;    // 0..1M-1
    const float* src;
    unsigned short *hi, *lo;
    if (idx < 524288) {
        const size_t e = (size_t)idx * 8;
        src = Q + e; hi = Qh + e; lo = Ql + e;
    } else {
        const int j = idx - 524288;
        const int t = j >> 17;
        const size_t e = (size_t)(j & 131071) * 8;
        src = (t==0 ? W0 : t==1 ? W1 : t==2 ? W2 : W3) + e;
        hi = wout + (size_t)t * 2097152 + e;
        lo = hi + 1048576;
    }
    float4 a = *(const float4*)src;
    float4 b = *(const float4*)(src + 4);
    float x[8] = {a.x,a.y,a.z,a.w,b.x,b.y,b.z,b.w};
    u16x8 h, l;
    split8(x, h, l);
    *(u16x8*)hi = h;
    *(u16x8*)lo = l;
}

// ---------------------------------------------------------------------------
// Split-bf16 MFMA GEMM. MODE 0: fp32 out. MODE 1: RoPE*QSC -> qb (B,H,S,dk).
// MODE 2: RoPE -> kb TILED. MODE 3: +bias -> vt TILED.   (verified rounds 4-7)
// ---------------------------------------------------------------------------
template <int MODE>
__global__ __launch_bounds__(512) void mfma_gemm(
    const unsigned short* __restrict__ Ah, const unsigned short* __restrict__ Al,
    const unsigned short* __restrict__ Wh, const unsigned short* __restrict__ Wl,
    const float* __restrict__ bias, void* __restrict__ OutP)
{
    __shared__ unsigned short lds[2][4][4096];
    const int tid = threadIdx.x;
    const int w = tid >> 6, lane = tid & 63;
    const int l15 = lane & 15, g4 = lane >> 4;
    const int wr = w >> 1, wc = w & 1;
    const int bx = blockIdx.x, by = blockIdx.y;

    const int tileId = w >> 1;
    const int halfT  = w & 1;
    const unsigned short* gsrc = (tileId==0) ? Ah : (tileId==1) ? Al : (tileId==2) ? Wh : Wl;
    const int row0 = (tileId < 2) ? bx * 128 : by * 128;
    const int r_l = lane >> 2, c_l = lane & 3;
    const int cs = c_l ^ (r_l & 3);
    const char* gp0 = (const char*)gsrc + (size_t)(row0 + halfT*64 + r_l) * 2048 + cs * 16;

    f32x4 acc[2][4];
    #pragma unroll
    for (int m = 0; m < 2; ++m)
        #pragma unroll
        for (int n = 0; n < 4; ++n) acc[m][n] = (f32x4){0.f,0.f,0.f,0.f};

    #define STAGE(T, BUF) do {                                              \
        const char* g_ = gp0 + (size_t)(T) * 64;                            \
        unsigned short* lb_ = &lds[BUF][tileId][halfT * 2048];              \
        gload_lds16(g_,          lb_);                                      \
        gload_lds16(g_ + 32768,  lb_ + 512);                                \
        gload_lds16(g_ + 65536,  lb_ + 1024);                               \
        gload_lds16(g_ + 98304,  lb_ + 1536);                               \
    } while (0)

    STAGE(0, 0);
    __syncthreads();

    for (int t = 0; t < 32; ++t) {
        const int cur = t & 1;
        if (t < 31) STAGE(t + 1, cur ^ 1);
        const unsigned short* lA_h = lds[cur][0];
        const unsigned short* lA_l = lds[cur][1];
        const unsigned short* lW_h = lds[cur][2];
        const unsigned short* lW_l = lds[cur][3];
        bf16x8 ah[2], al2[2], wh4[4], wl4[4];
        #pragma unroll
        for (int m = 0; m < 2; ++m) {
            const int R = wr*32 + m*16 + l15;
            const int off = R*32 + ((g4 ^ (R & 3)) << 3);
            ah[m]  = *(const bf16x8*)(lA_h + off);
            al2[m] = *(const bf16x8*)(lA_l + off);
        }
        #pragma unroll
        for (int n = 0; n < 4; ++n) {
            const int R = wc*64 + n*16 + l15;
            const int off = R*32 + ((g4 ^ (R & 3)) << 3);
            wh4[n] = *(const bf16x8*)(lW_h + off);
            wl4[n] = *(const bf16x8*)(lW_l + off);
        }
        #pragma unroll
        for (int m = 0; m < 2; ++m)
            #pragma unroll
            for (int n = 0; n < 4; ++n) {
                acc[m][n] = __builtin_amdgcn_mfma_f32_16x16x32_bf16(ah[m],  wh4[n], acc[m][n], 0,0,0);
                acc[m][n] = __builtin_amdgcn_mfma_f32_16x16x32_bf16(ah[m],  wl4[n], acc[m][n], 0,0,0);
                acc[m][n] = __builtin_amdgcn_mfma_f32_16x16x32_bf16(al2[m], wh4[n], acc[m][n], 0,0,0);
            }
        __syncthreads();
    }
    #undef STAGE

    const int colBase = by*128 + wc*64;
    const int rowBase = bx*128 + wr*32;

    if constexpr (MODE == 0) {
        float* Out = (float*)OutP;
        #pragma unroll
        for (int m = 0; m < 2; ++m) {
            const int row = rowBase + m*16 + g4*4;
            #pragma unroll
            for (int n = 0; n < 4; ++n) {
                const int col = colBase + n*16 + l15;
                const float bb = bias[col];
                #pragma unroll
                for (int r = 0; r < 4; ++r)
                    Out[(size_t)(row + r) * 1024 + col] = acc[m][n][r] + bb;
            }
        }
    } else if constexpr (MODE == 1 || MODE == 2) {
        unsigned short* Out = (unsigned short*)OutP;
        const int h = colBase >> 6;
        const float QSC = (MODE == 1) ? 0.125f * 1.44269504088896340736f : 1.0f;
        #pragma unroll
        for (int m = 0; m < 2; ++m) {
            const int srow0 = rowBase + m*16 + g4*4;
            const int b = srow0 >> 11;
            unsigned short* hb2 = Out + (size_t)(b*H_ + h) * S_ * DK;
            #pragma unroll
            for (int n = 0; n < 2; ++n) {
                const int d = n*16 + l15;
                const float invf = exp2f((float)d * -0.4152410118609203f);
                const float b1 = bias[h*64 + d], b2 = bias[h*64 + d + 32];
                #pragma unroll
                for (int r = 0; r < 4; ++r) {
                    const int s = (srow0 + r) & 2047;
                    const float x1 = acc[m][n][r]   + b1;
                    const float x2 = acc[m][n+2][r] + b2;
                    float sn, cc;
                    __sincosf((float)s * invf, &sn, &cc);
                    const float o1 = (x1*cc - x2*sn) * QSC;
                    const float o2 = (x2*cc + x1*sn) * QSC;
                    if (MODE == 1) {
                        unsigned short* dst = hb2 + (size_t)s * DK;
                        dst[d]      = f2bf(o1);
                        dst[d + 32] = f2bf(o2);
                    } else {
                        unsigned short* tb = hb2 + (s >> 6) * 4096 + (s & 63) * 8;
                        tb[(d >> 3) * 512 + (d & 7)]        = f2bf(o1);
                        tb[(d >> 3) * 512 + 2048 + (d & 7)] = f2bf(o2);
                    }
                }
            }
        }
    } else {   // MODE 3: vt TILED
        unsigned short* Out = (unsigned short*)OutP;
        const int h = colBase >> 6;
        #pragma unroll
        for (int m = 0; m < 2; ++m) {
            const int srow0 = rowBase + m*16 + g4*4;
            const int b = srow0 >> 11, s0 = srow0 & 2047;
            unsigned short* tb = Out + (size_t)(b*H_ + h) * S_ * DK
                               + (s0 >> 6) * 4096 + ((s0 & 63) >> 3) * 512 + (s0 & 7);
            #pragma unroll
            for (int n = 0; n < 4; ++n) {
                const int d = n*16 + l15;
                const float bb = bias[h*64 + d];
                u16x4 pk;
                #pragma unroll
                for (int r = 0; r < 4; ++r) pk[r] = f2bf(acc[m][n][r] + bb);
                *(u16x4*)(tb + d * 8) = pk;
            }
        }
    }
}

// ---------------------------------------------------------------------------
// 32x32-MFMA flash attention. 8 waves x 32 q = 256 q/block; grid 256
// (1 block/CU, 2 waves/SIMD like round 7, but single staging domain).
// KVBLK=128 (2 global 64-key tiles per iter): half the barriers/staging calls
// of round 7. Register softmax (no max-tracking), pre-tiled conflict-free K/V,
// in-register P build. XCD-grouped bh (4 bh per XCD, KV L2-resident).
// LDS: 2 bufs x (K 16K | V 16K) = 64 KB.
// ---------------------------------------------------------------------------
__global__ __launch_bounds__(512, 1) void attn_mfma6(
    const unsigned short* __restrict__ Qb, const unsigned short* __restrict__ Kb,
    const unsigned short* __restrict__ Vt,
    unsigned short* __restrict__ Xh, unsigned short* __restrict__ Xl)
{
    __shared__ __align__(16) char lds[65536];
    const unsigned bid = blockIdx.x;             // 256 blocks
    const int xcd = bid & 7, idx = bid >> 3;     // idx 0..31
    const int bh  = xcd * 4 + (idx >> 3);        // 4 bh per XCD
    const int qt  = idx & 7;                     // 8 q-tiles of 256
    const int tid = threadIdx.x;
    const int w = tid >> 6, lane = tid & 63;
    const int l31 = lane & 31, hi = lane >> 5;
    const size_t bhO = (size_t)bh * S_ * DK;
    const int q0 = qt * 256 + w * 32;

    // staging: 32 units of 1KB per buf (K 16, V 16); wave w stages units w*4..+3
    const int u0   = w * 4;                 // first unit
    const int isV  = u0 >> 4;               // all 4 units same half (K or V)
    const int u15  = u0 & 15;
    const int su0  = u15 >> 3;              // units don't cross subtile? u15 0,4,8,12:
                                            // units u15..u15+3 stay in one subtile half
    const unsigned short* sb = (isV ? Vt : Kb) + bhO;
    const int ch0 = u15 & 7;                // 0 or 4
    // dest base for unit u15+i: su(u)=((u15+i)>>3) — with u15 in {0,4,8,12}, i<4:
    // su is constant per wave ✓ (0,0,1,1 for w mod 4 = 0..3)
    char* const dbase = lds; // indexed in macro

    // Q B-fragments: col=q=q0+l31, k = ks*16 + hi*8 + j
    bf16x8 qf[4];
    #pragma unroll
    for (int ks = 0; ks < 4; ++ks)
        qf[ks] = *(const bf16x8*)(Qb + bhO + (size_t)(q0 + l31) * DK + ks*16 + hi*8);

    f32x16 oT[2];
    #pragma unroll
    for (int dh = 0; dh < 2; ++dh)
        #pragma unroll
        for (int r = 0; r < 16; ++r) oT[dh][r] = 0.f;
    float l_ = 0.f;

    #define ASTAGE(T, BUF) do {                                                     \
        const unsigned short* g_ = sb + (size_t)((T)*2 + su0) * 4096 + ch0 * 512    \
                                   + lane * 8;                                      \
        char* d_ = dbase + (BUF)*32768 + isV*16384 + su0*8192 + ch0*1024 + lane*16; \
        gload_lds16(g_,         d_);                                                \
        gload_lds16(g_ + 512,   d_ + 1024);                                         \
        gload_lds16(g_ + 1024,  d_ + 2048);                                         \
        gload_lds16(g_ + 1536,  d_ + 3072);                                         \
    } while (0)

    ASTAGE(0, 0);
    __syncthreads();

    for (int t = 0; t < 16; ++t) {
        const int cur = t & 1;
        if (t < 15) ASTAGE(t + 1, cur ^ 1);
        const char* Kl = lds + cur * 32768;
        const char* Vl = Kl + 16384;

        // ---- S^T = K · Q^T over 128 keys: 4 key-blocks of 32 ----
        f32x16 s2[4];
        __builtin_amdgcn_s_setprio(1);
        #pragma unroll
        for (int kb2 = 0; kb2 < 4; ++kb2) {
            f32x16 a;
            #pragma unroll
            for (int r = 0; r < 16; ++r) a[r] = 0.f;
            const char* kbase = Kl + (kb2 >> 1) * 8192 + ((kb2 & 1) * 32 + l31) * 16;
            #pragma unroll
            for (int ks = 0; ks < 4; ++ks) {
                bf16x8 kf = *(const bf16x8*)(kbase + (ks*2 + hi) * 1024);
                a = __builtin_amdgcn_mfma_f32_32x32x16_bf16(kf, qf[ks], a, 0, 0, 0);
            }
            s2[kb2] = a;
        }
        __builtin_amdgcn_s_setprio(0);

        // ---- softmax, no max subtraction (bounded scores) ----
        {
            float lsum = 0.f;
            #pragma unroll
            for (int kb2 = 0; kb2 < 4; ++kb2)
                #pragma unroll
                for (int r = 0; r < 16; ++r) {
                    const float p = EXP2(s2[kb2][r]);
                    s2[kb2][r] = p; lsum += p;
                }
            l_ += lsum;
        }

        // ---- PV: 8 key-steps of 16; P-frags built in registers ----
        #pragma unroll
        for (int ks2 = 0; ks2 < 8; ++ks2) {
            const int kb2 = ks2 >> 1;
            const int R0  = (ks2 & 1) * 8;
            const unsigned pkA0 = cvtpk(s2[kb2][R0+0], s2[kb2][R0+1]);
            const unsigned pkA1 = cvtpk(s2[kb2][R0+2], s2[kb2][R0+3]);
            const unsigned pkB0 = cvtpk(s2[kb2][R0+4], s2[kb2][R0+5]);
            const unsigned pkB1 = cvtpk(s2[kb2][R0+6], s2[kb2][R0+7]);
            const unsigned snd0 = hi ? pkA0 : pkB0;
            const unsigned snd1 = hi ? pkA1 : pkB1;
            const unsigned rcv0 = __shfl_xor(snd0, 32, 64);
            const unsigned rcv1 = __shfl_xor(snd1, 32, 64);
            union { unsigned u[4]; bf16x8 v; } pf;
            pf.u[0] = hi ? rcv0 : pkA0;
            pf.u[1] = hi ? rcv1 : pkA1;
            pf.u[2] = hi ? pkB0 : rcv0;
            pf.u[3] = hi ? pkB1 : rcv1;
            const char* vbase = Vl + (ks2 >> 2) * 8192 + (((ks2 & 3) * 2) + hi) * 1024;
            __builtin_amdgcn_s_setprio(1);
            #pragma unroll
            for (int dh = 0; dh < 2; ++dh) {
                bf16x8 vf = *(const bf16x8*)(vbase + (dh*32 + l31) * 16);
                oT[dh] = __builtin_amdgcn_mfma_f32_32x32x16_bf16(vf, pf.v, oT[dh], 0, 0, 0);
            }
            __builtin_amdgcn_s_setprio(0);
        }
        __syncthreads();
    }
    #undef ASTAGE

    // ---- epilogue: combine l halves, O^T/l -> Xh/Xl bf16 splits ----
    l_ += __shfl_xor(l_, 32, 64);
    const float inv = 1.0f / l_;
    const int b = bh >> 4, h = bh & 15;
    const int q = q0 + l31;
    unsigned short* xh = Xh + (((size_t)b * S_ + q) * H_ + h) * DK;
    unsigned short* xl = Xl + (((size_t)b * S_ + q) * H_ + h) * DK;
    #pragma unroll
    for (int dh = 0; dh < 2; ++dh)
        #pragma unroll
        for (int tt = 0; tt < 4; ++tt) {
            const int dk0 = dh*32 + tt*8 + hi*4;
            u16x4 hv, lv;
            #pragma unroll
            for (int r = 0; r < 4; ++r) {
                const float o = oT[dh][tt*4 + r] * inv;
                const unsigned short hb = f2bf(o);
                hv[r] = hb;
                lv[r] = f2bf(o - bf2f(hb));
            }
            *(u16x4*)(xh + dk0) = hv;
            *(u16x4*)(xl + dk0) = lv;
        }
}

// ---------------------------------------------------------------------------
extern "C" void kernel_launch(void* const* d_in, const int* in_sizes, int n_in,
                              void* d_out, int out_size, void* d_ws, size_t ws_size,
                              hipStream_t stream)
{
    const float* query = (const float*)d_in[0];
    const float* key   = (const float*)d_in[1];
    const float* value = (const float*)d_in[2];
    const float* Wq = (const float*)d_in[3];  const float* bq = (const float*)d_in[4];
    const float* Wk = (const float*)d_in[5];  const float* bk = (const float*)d_in[6];
    const float* Wv = (const float*)d_in[7];  const float* bv = (const float*)d_in[8];
    const float* Wo = (const float*)d_in[9];  const float* bo = (const float*)d_in[10];
    float* out = (float*)d_out;

    char* ws = (char*)d_ws;
    const size_t MB = (size_t)1 << 20;
    unsigned short* QAh = (unsigned short*)(ws + 0*MB);
    unsigned short* QAl = (unsigned short*)(ws + 8*MB);
    unsigned short* qb  = (unsigned short*)(ws + 16*MB);
    unsigned short* KAh = (unsigned short*)(ws + 24*MB);
    unsigned short* KAl = (unsigned short*)(ws + 32*MB);
    unsigned short* kb  = (unsigned short*)(ws + 40*MB);
    unsigned short* VAh = (unsigned short*)(ws + 0*MB);
    unsigned short* VAl = (unsigned short*)(ws + 8*MB);
    unsigned short* vt  = (unsigned short*)(ws + 24*MB);
    unsigned short* Xh  = (unsigned short*)(ws + 0*MB);
    unsigned short* Xl  = (unsigned short*)(ws + 8*MB);
    unsigned short* wsp = (unsigned short*)(ws + 48*MB);
    unsigned short* Wqh = wsp;               unsigned short* Wql = wsp + 1048576;
    unsigned short* Wkh = wsp + 2097152;     unsigned short* Wkl = wsp + 3145728;
    unsigned short* Wvh = wsp + 4194304;     unsigned short* Wvl = wsp + 5242880;
    unsigned short* Woh = wsp + 6291456;     unsigned short* Wol = wsp + 7340032;

    dim3 ggrid(32, 8);

    splitQW<<<4096, 256, 0, stream>>>(query, Wq, Wk, Wv, Wo, QAh, QAl, wsp);
    mfma_gemm<1><<<ggrid, 512, 0, stream>>>(QAh, QAl, Wqh, Wql, bq, qb);

    asplit<<<2048, 256, 0, stream>>>(key, KAh, KAl);
    mfma_gemm<2><<<ggrid, 512, 0, stream>>>(KAh, KAl, Wkh, Wkl, bk, kb);

    asplit<<<2048, 256, 0, stream>>>(value, VAh, VAl);
    mfma_gemm<3><<<ggrid, 512, 0, stream>>>(VAh, VAl, Wvh, Wvl, bv, vt);

    attn_mfma6<<<256, 512, 0, stream>>>(qb, kb, vt, Xh, Xl);

    mfma_gemm<0><<<ggrid, 512, 0, stream>>>(Xh, Xl, Woh, Wol, bo, out);
}

// Round 10
// 198.942 us; speedup vs baseline: 1.1011x; 1.0017x over previous
//
#include <hip/hip_runtime.h>
#include <hip/hip_bf16.h>
#include <math.h>

// B=2, S=2048, D=1024, H=16, dk=64.
// wsplit4 -> MFMA split-GEMMs with FUSED A-split (fp32 A staged in-register,
// split to hi/lo bf16, ds_write) + fused RoPE / tiled-V epilogues
// -> 32x32-MFMA flash attention (8-wave, KVBLK=128, register softmax)
// -> MFMA split-GEMM (pre-split X from attn) -> out.
//
// Tiled K layout per (b,h): 64-key tile t at t*4096 elems; within tile:
//   elem(key r, dk d) at chunk(d>>3)*512 + r*8 + (d&7).
// Tiled V layout per (b,h): 64-key tile t at t*4096; elem(dk dkr, key s):
//   chunk((s&63)>>3)*512 + dkr*8 + (s&7).
//
// ws (64 MB):
//  [0,8)   Xh   [8,16) Xl   (written by attn, read by gemm<0>)
//  [16,24) qb (bf16 B,H,S,dk)
//  [24,32) vt (bf16 tiled)
//  [40,48) kb (bf16 tiled)
//  [48,64) W splits (hi/lo per weight)

#define B_ 2
#define S_ 2048
#define D_ 1024
#define H_ 16
#define DK 64

typedef __attribute__((ext_vector_type(8)))  __bf16 bf16x8;
typedef __attribute__((ext_vector_type(4)))  float  f32x4;
typedef __attribute__((ext_vector_type(16))) float  f32x16;
typedef __attribute__((ext_vector_type(8)))  unsigned short u16x8;
typedef __attribute__((ext_vector_type(4)))  unsigned short u16x4;

#if __has_builtin(__builtin_amdgcn_exp2f)
#define EXP2(x) __builtin_amdgcn_exp2f(x)
#else
#define EXP2(x) exp2f(x)
#endif

static __device__ __forceinline__ unsigned short f2bf(float x) {
    union { float f; unsigned u; } v; v.f = x;
    unsigned r = v.u + 0x7FFFu + ((v.u >> 16) & 1u);   // RNE
    return (unsigned short)(r >> 16);
}
static __device__ __forceinline__ float bf2f(unsigned short h) {
    union { unsigned u; float f; } v; v.u = ((unsigned)h) << 16;
    return v.f;
}
static __device__ __forceinline__ unsigned cvtpk(float lo, float hi) {
    unsigned r;
    asm("v_cvt_pk_bf16_f32 %0, %1, %2" : "=v"(r) : "v"(lo), "v"(hi));
    return r;
}
static __device__ __forceinline__ void gload_lds16(const void* g, void* l) {
    __builtin_amdgcn_global_load_lds(
        (const __attribute__((address_space(1))) void*)g,
        (__attribute__((address_space(3))) void*)l, 16, 0, 0);
}
static __device__ __forceinline__ void split8v(float4 a, float4 b, u16x8& h, u16x8& l) {
    float x[8] = {a.x,a.y,a.z,a.w,b.x,b.y,b.z,b.w};
    #pragma unroll
    for (int j = 0; j < 8; ++j) {
        unsigned short hb = f2bf(x[j]);
        h[j] = hb;
        l[j] = f2bf(x[j] - bf2f(hb));
    }
}

// ---------------------------------------------------------------------------
// 4-weight fp32 -> bf16 hi/lo split. out: per weight t, hi @ t*2M, lo @ +1M.
// ---------------------------------------------------------------------------
__global__ __launch_bounds__(256) void wsplit4(
    const float* __restrict__ W0, const float* __restrict__ W1,
    const float* __restrict__ W2, const float* __restrict__ W3,
    unsigned short* __restrict__ out)
{
    const int idx = blockIdx.x * 256 + threadIdx.x;
    const int t = idx >> 17;
    const size_t e = (size_t)(idx & 131071) * 8;
    const float* src = (t==0 ? W0 : t==1 ? W1 : t==2 ? W2 : W3) + e;
    unsigned short* hi = out + (size_t)t * 2097152 + e;
    unsigned short* lo = hi + 1048576;
    float4 a = *(const float4*)src;
    float4 b = *(const float4*)(src + 4);
    u16x8 h, l;
    split8v(a, b, h, l);
    *(u16x8*)hi = h;
    *(u16x8*)lo = l;
}

// ---------------------------------------------------------------------------
// Split-bf16 MFMA GEMM, C = A·W^T + bias (M=4096,N=1024,K=1024), 128x128 tile,
// BK=32, 8 waves, double-buffered LDS.
// ASPLIT=1: A0 = raw fp32 A; staged in-register (global_load -> split -> ds_write,
//           issued before / written after the compute phase). W via global_load_lds
//           (waves 4-7). Deletes the standalone asplit kernels.
// ASPLIT=0: A0/A1 = pre-split Ah/Al, all staging via global_load_lds (8 waves).
// MODE 0: fp32 out. MODE 1: RoPE*QSC -> qb. MODE 2: RoPE -> kb TILED.
// MODE 3: +bias -> vt TILED.
// ---------------------------------------------------------------------------
template <int MODE, int ASPLIT>
__global__ __launch_bounds__(512) void mfma_gemm(
    const void* __restrict__ A0, const unsigned short* __restrict__ A1,
    const unsigned short* __restrict__ Wh, const unsigned short* __restrict__ Wl,
    const float* __restrict__ bias, void* __restrict__ OutP)
{
    __shared__ __align__(16) unsigned short lds[2][4][4096];
    const int tid = threadIdx.x;
    const int w = tid >> 6, lane = tid & 63;
    const int l15 = lane & 15, g4 = lane >> 4;
    const int wr = w >> 1, wc = w & 1;
    const int bx = blockIdx.x, by = blockIdx.y;

    // ---- gload_lds staging geometry (tensors: 0=Ah 1=Al 2=Wh 3=Wl) ----
    const int tileId = w >> 1;
    const int halfT  = w & 1;
    const unsigned short* gsrc;
    if (ASPLIT) gsrc = (tileId == 3) ? Wl : Wh;           // waves<4 unused
    else        gsrc = (tileId==0) ? (const unsigned short*)A0 :
                       (tileId==1) ? A1 : (tileId==2) ? Wh : Wl;
    const int row0 = (tileId < 2) ? bx * 128 : by * 128;
    const int r_l = lane >> 2, c_l = lane & 3;
    const int cs = c_l ^ (r_l & 3);
    const char* gp0 = (const char*)gsrc + (size_t)(row0 + halfT*64 + r_l) * 2048 + cs * 16;

    // ---- reg-staged A geometry (ASPLIT) ----
    const int arow = tid >> 2;              // 0..127
    const int ac   = tid & 3;               // 8-elem chunk 0..3
    const float* agp = ASPLIT ? (const float*)A0 + (size_t)(bx*128 + arow) * 1024 + ac * 8
                              : nullptr;
    const int aoff = arow * 32 + ((ac ^ (arow & 3)) << 3);

    f32x4 acc[2][4];
    #pragma unroll
    for (int m = 0; m < 2; ++m)
        #pragma unroll
        for (int n = 0; n < 4; ++n) acc[m][n] = (f32x4){0.f,0.f,0.f,0.f};

    #define WSTAGE(T, BUF) do {                                             \
        const char* g_ = gp0 + (size_t)(T) * 64;                            \
        unsigned short* lb_ = &lds[BUF][tileId][halfT * 2048];              \
        gload_lds16(g_,          lb_);                                      \
        gload_lds16(g_ + 32768,  lb_ + 512);                                \
        gload_lds16(g_ + 65536,  lb_ + 1024);                               \
        gload_lds16(g_ + 98304,  lb_ + 1536);                               \
    } while (0)

    // ---- prologue: stage tile 0 into buf 0 ----
    if (ASPLIT) {
        float4 p0 = *(const float4*)(agp);
        float4 p1 = *(const float4*)(agp + 4);
        if (w >= 4) WSTAGE(0, 0);
        u16x8 h, l;
        split8v(p0, p1, h, l);
        *(u16x8*)&lds[0][0][aoff] = h;
        *(u16x8*)&lds[0][1][aoff] = l;
    } else {
        WSTAGE(0, 0);
    }
    __syncthreads();

    for (int t = 0; t < 32; ++t) {
        const int cur = t & 1;
        float4 n0, n1;
        if (t < 31) {
            if (ASPLIT) {
                n0 = *(const float4*)(agp + (t+1)*32);
                n1 = *(const float4*)(agp + (t+1)*32 + 4);
                if (w >= 4) WSTAGE(t + 1, cur ^ 1);
            } else {
                WSTAGE(t + 1, cur ^ 1);
            }
        }
        // ---- compute buf[cur] ----
        const unsigned short* lA_h = lds[cur][0];
        const unsigned short* lA_l = lds[cur][1];
        const unsigned short* lW_h = lds[cur][2];
        const unsigned short* lW_l = lds[cur][3];
        bf16x8 ah[2], al2[2], wh4[4], wl4[4];
        #pragma unroll
        for (int m = 0; m < 2; ++m) {
            const int R = wr*32 + m*16 + l15;
            const int off = R*32 + ((g4 ^ (R & 3)) << 3);
            ah[m]  = *(const bf16x8*)(lA_h + off);
            al2[m] = *(const bf16x8*)(lA_l + off);
        }
        #pragma unroll
        for (int n = 0; n < 4; ++n) {
            const int R = wc*64 + n*16 + l15;
            const int off = R*32 + ((g4 ^ (R & 3)) << 3);
            wh4[n] = *(const bf16x8*)(lW_h + off);
            wl4[n] = *(const bf16x8*)(lW_l + off);
        }
        #pragma unroll
        for (int m = 0; m < 2; ++m)
            #pragma unroll
            for (int n = 0; n < 4; ++n) {
                acc[m][n] = __builtin_amdgcn_mfma_f32_16x16x32_bf16(ah[m],  wh4[n], acc[m][n], 0,0,0);
                acc[m][n] = __builtin_amdgcn_mfma_f32_16x16x32_bf16(ah[m],  wl4[n], acc[m][n], 0,0,0);
                acc[m][n] = __builtin_amdgcn_mfma_f32_16x16x32_bf16(al2[m], wh4[n], acc[m][n], 0,0,0);
            }
        // ---- write next A tile (regs -> split -> LDS) after compute ----
        if (ASPLIT && t < 31) {
            u16x8 h, l;
            split8v(n0, n1, h, l);
            *(u16x8*)&lds[cur ^ 1][0][aoff] = h;
            *(u16x8*)&lds[cur ^ 1][1][aoff] = l;
        }
        __syncthreads();
    }
    #undef WSTAGE

    const int colBase = by*128 + wc*64;
    const int rowBase = bx*128 + wr*32;

    if constexpr (MODE == 0) {
        float* Out = (float*)OutP;
        #pragma unroll
        for (int m = 0; m < 2; ++m) {
            const int row = rowBase + m*16 + g4*4;
            #pragma unroll
            for (int n = 0; n < 4; ++n) {
                const int col = colBase + n*16 + l15;
                const float bb = bias[col];
                #pragma unroll
                for (int r = 0; r < 4; ++r)
                    Out[(size_t)(row + r) * 1024 + col] = acc[m][n][r] + bb;
            }
        }
    } else if constexpr (MODE == 1 || MODE == 2) {
        unsigned short* Out = (unsigned short*)OutP;
        const int h = colBase >> 6;
        const float QSC = (MODE == 1) ? 0.125f * 1.44269504088896340736f : 1.0f;
        #pragma unroll
        for (int m = 0; m < 2; ++m) {
            const int srow0 = rowBase + m*16 + g4*4;
            const int b = srow0 >> 11;
            unsigned short* hb2 = Out + (size_t)(b*H_ + h) * S_ * DK;
            #pragma unroll
            for (int n = 0; n < 2; ++n) {
                const int d = n*16 + l15;
                const float invf = exp2f((float)d * -0.4152410118609203f);
                const float b1 = bias[h*64 + d], b2 = bias[h*64 + d + 32];
                #pragma unroll
                for (int r = 0; r < 4; ++r) {
                    const int s = (srow0 + r) & 2047;
                    const float x1 = acc[m][n][r]   + b1;
                    const float x2 = acc[m][n+2][r] + b2;
                    float sn, cc;
                    __sincosf((float)s * invf, &sn, &cc);
                    const float o1 = (x1*cc - x2*sn) * QSC;
                    const float o2 = (x2*cc + x1*sn) * QSC;
                    if (MODE == 1) {
                        unsigned short* dst = hb2 + (size_t)s * DK;
                        dst[d]      = f2bf(o1);
                        dst[d + 32] = f2bf(o2);
                    } else {
                        unsigned short* tb = hb2 + (s >> 6) * 4096 + (s & 63) * 8;
                        tb[(d >> 3) * 512 + (d & 7)]        = f2bf(o1);
                        tb[(d >> 3) * 512 + 2048 + (d & 7)] = f2bf(o2);
                    }
                }
            }
        }
    } else {   // MODE 3: vt TILED
        unsigned short* Out = (unsigned short*)OutP;
        const int h = colBase >> 6;
        #pragma unroll
        for (int m = 0; m < 2; ++m) {
            const int srow0 = rowBase + m*16 + g4*4;
            const int b = srow0 >> 11, s0 = srow0 & 2047;
            unsigned short* tb = Out + (size_t)(b*H_ + h) * S_ * DK
                               + (s0 >> 6) * 4096 + ((s0 & 63) >> 3) * 512 + (s0 & 7);
            #pragma unroll
            for (int n = 0; n < 4; ++n) {
                const int d = n*16 + l15;
                const float bb = bias[h*64 + d];
                u16x4 pk;
                #pragma unroll
                for (int r = 0; r < 4; ++r) pk[r] = f2bf(acc[m][n][r] + bb);
                *(u16x4*)(tb + d * 8) = pk;
            }
        }
    }
}

// ---------------------------------------------------------------------------
// 32x32-MFMA flash attention (unchanged from round 9 — best so far).
// 8 waves x 32 q = 256 q/block; grid 256; KVBLK=128; register softmax
// (no max-tracking, bounded scores); pre-tiled conflict-free K/V staging;
// XCD-grouped bh. LDS: 2 bufs x (K 16K | V 16K) = 64 KB.
// ---------------------------------------------------------------------------
__global__ __launch_bounds__(512, 1) void attn_mfma6(
    const unsigned short* __restrict__ Qb, const unsigned short* __restrict__ Kb,
    const unsigned short* __restrict__ Vt,
    unsigned short* __restrict__ Xh, unsigned short* __restrict__ Xl)
{
    __shared__ __align__(16) char lds[65536];
    const unsigned bid = blockIdx.x;             // 256 blocks
    const int xcd = bid & 7, idx = bid >> 3;     // idx 0..31
    const int bh  = xcd * 4 + (idx >> 3);        // 4 bh per XCD
    const int qt  = idx & 7;                     // 8 q-tiles of 256
    const int tid = threadIdx.x;
    const int w = tid >> 6, lane = tid & 63;
    const int l31 = lane & 31, hi = lane >> 5;
    const size_t bhO = (size_t)bh * S_ * DK;
    const int q0 = qt * 256 + w * 32;

    const int u0   = w * 4;
    const int isV  = u0 >> 4;
    const int u15  = u0 & 15;
    const int su0  = u15 >> 3;
    const unsigned short* sb = (isV ? Vt : Kb) + bhO;
    const int ch0 = u15 & 7;
    char* const dbase = lds;

    bf16x8 qf[4];
    #pragma unroll
    for (int ks = 0; ks < 4; ++ks)
        qf[ks] = *(const bf16x8*)(Qb + bhO + (size_t)(q0 + l31) * DK + ks*16 + hi*8);

    f32x16 oT[2];
    #pragma unroll
    for (int dh = 0; dh < 2; ++dh)
        #pragma unroll
        for (int r = 0; r < 16; ++r) oT[dh][r] = 0.f;
    float l_ = 0.f;

    #define ASTAGE(T, BUF) do {                                                     \
        const unsigned short* g_ = sb + (size_t)((T)*2 + su0) * 4096 + ch0 * 512    \
                                   + lane * 8;                                      \
        char* d_ = dbase + (BUF)*32768 + isV*16384 + su0*8192 + ch0*1024 + lane*16; \
        gload_lds16(g_,         d_);                                                \
        gload_lds16(g_ + 512,   d_ + 1024);                                         \
        gload_lds16(g_ + 1024,  d_ + 2048);                                         \
        gload_lds16(g_ + 1536,  d_ + 3072);                                         \
    } while (0)

    ASTAGE(0, 0);
    __syncthreads();

    for (int t = 0; t < 16; ++t) {
        const int cur = t & 1;
        if (t < 15) ASTAGE(t + 1, cur ^ 1);
        const char* Kl = lds + cur * 32768;
        const char* Vl = Kl + 16384;

        f32x16 s2[4];
        __builtin_amdgcn_s_setprio(1);
        #pragma unroll
        for (int kb2 = 0; kb2 < 4; ++kb2) {
            f32x16 a;
            #pragma unroll
            for (int r = 0; r < 16; ++r) a[r] = 0.f;
            const char* kbase = Kl + (kb2 >> 1) * 8192 + ((kb2 & 1) * 32 + l31) * 16;
            #pragma unroll
            for (int ks = 0; ks < 4; ++ks) {
                bf16x8 kf = *(const bf16x8*)(kbase + (ks*2 + hi) * 1024);
                a = __builtin_amdgcn_mfma_f32_32x32x16_bf16(kf, qf[ks], a, 0, 0, 0);
            }
            s2[kb2] = a;
        }
        __builtin_amdgcn_s_setprio(0);

        {
            float lsum = 0.f;
            #pragma unroll
            for (int kb2 = 0; kb2 < 4; ++kb2)
                #pragma unroll
                for (int r = 0; r < 16; ++r) {
                    const float p = EXP2(s2[kb2][r]);
                    s2[kb2][r] = p; lsum += p;
                }
            l_ += lsum;
        }

        #pragma unroll
        for (int ks2 = 0; ks2 < 8; ++ks2) {
            const int kb2 = ks2 >> 1;
            const int R0  = (ks2 & 1) * 8;
            const unsigned pkA0 = cvtpk(s2[kb2][R0+0], s2[kb2][R0+1]);
            const unsigned pkA1 = cvtpk(s2[kb2][R0+2], s2[kb2][R0+3]);
            const unsigned pkB0 = cvtpk(s2[kb2][R0+4], s2[kb2][R0+5]);
            const unsigned pkB1 = cvtpk(s2[kb2][R0+6], s2[kb2][R0+7]);
            const unsigned snd0 = hi ? pkA0 : pkB0;
            const unsigned snd1 = hi ? pkA1 : pkB1;
            const unsigned rcv0 = __shfl_xor(snd0, 32, 64);
            const unsigned rcv1 = __shfl_xor(snd1, 32, 64);
            union { unsigned u[4]; bf16x8 v; } pf;
            pf.u[0] = hi ? rcv0 : pkA0;
            pf.u[1] = hi ? rcv1 : pkA1;
            pf.u[2] = hi ? pkB0 : rcv0;
            pf.u[3] = hi ? pkB1 : rcv1;
            const char* vbase = Vl + (ks2 >> 2) * 8192 + (((ks2 & 3) * 2) + hi) * 1024;
            __builtin_amdgcn_s_setprio(1);
            #pragma unroll
            for (int dh = 0; dh < 2; ++dh) {
                bf16x8 vf = *(const bf16x8*)(vbase + (dh*32 + l31) * 16);
                oT[dh] = __builtin_amdgcn_mfma_f32_32x32x16_bf16(vf, pf.v, oT[dh], 0, 0, 0);
            }
            __builtin_amdgcn_s_setprio(0);
        }
        __syncthreads();
    }
    #undef ASTAGE

    l_ += __shfl_xor(l_, 32, 64);
    const float inv = 1.0f / l_;
    const int b = bh >> 4, h = bh & 15;
    const int q = q0 + l31;
    unsigned short* xh = Xh + (((size_t)b * S_ + q) * H_ + h) * DK;
    unsigned short* xl = Xl + (((size_t)b * S_ + q) * H_ + h) * DK;
    #pragma unroll
    for (int dh = 0; dh < 2; ++dh)
        #pragma unroll
        for (int tt = 0; tt < 4; ++tt) {
            const int dk0 = dh*32 + tt*8 + hi*4;
            u16x4 hv, lv;
            #pragma unroll
            for (int r = 0; r < 4; ++r) {
                const float o = oT[dh][tt*4 + r] * inv;
                const unsigned short hb = f2bf(o);
                hv[r] = hb;
                lv[r] = f2bf(o - bf2f(hb));
            }
            *(u16x4*)(xh + dk0) = hv;
            *(u16x4*)(xl + dk0) = lv;
        }
}

// ---------------------------------------------------------------------------
extern "C" void kernel_launch(void* const* d_in, const int* in_sizes, int n_in,
                              void* d_out, int out_size, void* d_ws, size_t ws_size,
                              hipStream_t stream)
{
    const float* query = (const float*)d_in[0];
    const float* key   = (const float*)d_in[1];
    const float* value = (const float*)d_in[2];
    const float* Wq = (const float*)d_in[3];  const float* bq = (const float*)d_in[4];
    const float* Wk = (const float*)d_in[5];  const float* bk = (const float*)d_in[6];
    const float* Wv = (const float*)d_in[7];  const float* bv = (const float*)d_in[8];
    const float* Wo = (const float*)d_in[9];  const float* bo = (const float*)d_in[10];
    float* out = (float*)d_out;

    char* ws = (char*)d_ws;
    const size_t MB = (size_t)1 << 20;
    unsigned short* Xh  = (unsigned short*)(ws + 0*MB);
    unsigned short* Xl  = (unsigned short*)(ws + 8*MB);
    unsigned short* qb  = (unsigned short*)(ws + 16*MB);
    unsigned short* vt  = (unsigned short*)(ws + 24*MB);
    unsigned short* kb  = (unsigned short*)(ws + 40*MB);
    unsigned short* wsp = (unsigned short*)(ws + 48*MB);
    unsigned short* Wqh = wsp;               unsigned short* Wql = wsp + 1048576;
    unsigned short* Wkh = wsp + 2097152;     unsigned short* Wkl = wsp + 3145728;
    unsigned short* Wvh = wsp + 4194304;     unsigned short* Wvl = wsp + 5242880;
    unsigned short* Woh = wsp + 6291456;     unsigned short* Wol = wsp + 7340032;

    dim3 ggrid(32, 8);

    wsplit4<<<2048, 256, 0, stream>>>(Wq, Wk, Wv, Wo, wsp);

    mfma_gemm<1,1><<<ggrid, 512, 0, stream>>>(query, nullptr, Wqh, Wql, bq, qb);
    mfma_gemm<2,1><<<ggrid, 512, 0, stream>>>(key,   nullptr, Wkh, Wkl, bk, kb);
    mfma_gemm<3,1><<<ggrid, 512, 0, stream>>>(value, nullptr, Wvh, Wvl, bv, vt);

    attn_mfma6<<<256, 512, 0, stream>>>(qb, kb, vt, Xh, Xl);

    mfma_gemm<0,0><<<ggrid, 512, 0, stream>>>(Xh, Xl, Woh, Wol, bo, out);
}

// Round 11
// 173.930 us; speedup vs baseline: 1.2594x; 1.1438x over previous
//
#include <hip/hip_runtime.h>
#include <hip/hip_bf16.h>
#include <math.h>

// B=2, S=2048, D=1024, H=16, dk=64.
// wsplit4 -> ONE fused tri-GEMM (q/k/v projections, fused A-split + RoPE /
// tiled-V epilogues) -> 32x32-MFMA flash attention (8-wave, KVBLK=128,
// register softmax, permlane32_swap P-exchange) -> MFMA split-GEMM -> out.
//
// Tiled K layout per (b,h): 64-key tile t at t*4096 elems; within tile:
//   elem(key r, dk d) at chunk(d>>3)*512 + r*8 + (d&7).
// Tiled V layout per (b,h): 64-key tile t at t*4096; elem(dk dkr, key s):
//   chunk((s&63)>>3)*512 + dkr*8 + (s&7).
//
// ws (64 MB):
//  [0,8)   Xh   [8,16) Xl   (written by attn, read by gemm<0>)
//  [16,24) qb (bf16 B,H,S,dk)
//  [24,32) vt (bf16 tiled)
//  [40,48) kb (bf16 tiled)
//  [48,64) W splits (hi/lo per weight)

#define B_ 2
#define S_ 2048
#define D_ 1024
#define H_ 16
#define DK 64

typedef __attribute__((ext_vector_type(8)))  __bf16 bf16x8;
typedef __attribute__((ext_vector_type(4)))  float  f32x4;
typedef __attribute__((ext_vector_type(16))) float  f32x16;
typedef __attribute__((ext_vector_type(8)))  unsigned short u16x8;
typedef __attribute__((ext_vector_type(4)))  unsigned short u16x4;

#if __has_builtin(__builtin_amdgcn_exp2f)
#define EXP2(x) __builtin_amdgcn_exp2f(x)
#else
#define EXP2(x) exp2f(x)
#endif

static __device__ __forceinline__ unsigned short f2bf(float x) {
    union { float f; unsigned u; } v; v.f = x;
    unsigned r = v.u + 0x7FFFu + ((v.u >> 16) & 1u);   // RNE
    return (unsigned short)(r >> 16);
}
static __device__ __forceinline__ float bf2f(unsigned short h) {
    union { unsigned u; float f; } v; v.u = ((unsigned)h) << 16;
    return v.f;
}
static __device__ __forceinline__ unsigned cvtpk(float lo, float hi) {
    unsigned r;
    asm("v_cvt_pk_bf16_f32 %0, %1, %2" : "=v"(r) : "v"(lo), "v"(hi));
    return r;
}
static __device__ __forceinline__ void gload_lds16(const void* g, void* l) {
    __builtin_amdgcn_global_load_lds(
        (const __attribute__((address_space(1))) void*)g,
        (__attribute__((address_space(3))) void*)l, 16, 0, 0);
}
static __device__ __forceinline__ void split8v(float4 a, float4 b, u16x8& h, u16x8& l) {
    float x[8] = {a.x,a.y,a.z,a.w,b.x,b.y,b.z,b.w};
    #pragma unroll
    for (int j = 0; j < 8; ++j) {
        unsigned short hb = f2bf(x[j]);
        h[j] = hb;
        l[j] = f2bf(x[j] - bf2f(hb));
    }
}

// ---------------------------------------------------------------------------
// 4-weight fp32 -> bf16 hi/lo split. out: per weight t, hi @ t*2M, lo @ +1M.
// ---------------------------------------------------------------------------
__global__ __launch_bounds__(256) void wsplit4(
    const float* __restrict__ W0, const float* __restrict__ W1,
    const float* __restrict__ W2, const float* __restrict__ W3,
    unsigned short* __restrict__ out)
{
    const int idx = blockIdx.x * 256 + threadIdx.x;
    const int t = idx >> 17;
    const size_t e = (size_t)(idx & 131071) * 8;
    const float* src = (t==0 ? W0 : t==1 ? W1 : t==2 ? W2 : W3) + e;
    unsigned short* hi = out + (size_t)t * 2097152 + e;
    unsigned short* lo = hi + 1048576;
    float4 a = *(const float4*)src;
    float4 b = *(const float4*)(src + 4);
    u16x8 h, l;
    split8v(a, b, h, l);
    *(u16x8*)hi = h;
    *(u16x8*)lo = l;
}

// ---------------------------------------------------------------------------
// Fused tri-GEMM: all three projections in one launch (blockIdx.z = problem).
// Per problem: C = A·W^T + bias, fp32 A reg-staged + split to hi/lo bf16 in
// LDS (waves 0-7 all), W staged via global_load_lds (waves 4-7).
// pid 0: RoPE*QSC -> qb (B,H,S,dk). pid 1: RoPE -> kb TILED. pid 2: vt TILED.
// ---------------------------------------------------------------------------
__global__ __launch_bounds__(512) void trigemm(
    const float* __restrict__ Aq, const float* __restrict__ Ak,
    const float* __restrict__ Av, const unsigned short* __restrict__ wsp,
    const float* __restrict__ bq, const float* __restrict__ bk,
    const float* __restrict__ bv,
    unsigned short* __restrict__ qb, unsigned short* __restrict__ kb,
    unsigned short* __restrict__ vt)
{
    __shared__ __align__(16) unsigned short lds[2][4][4096];
    const int pid = blockIdx.z;
    const float* A    = (pid==0) ? Aq : (pid==1) ? Ak : Av;
    const float* bias = (pid==0) ? bq : (pid==1) ? bk : bv;
    const unsigned short* Wh = wsp + (size_t)pid * 2097152;
    const unsigned short* Wl = Wh + 1048576;

    const int tid = threadIdx.x;
    const int w = tid >> 6, lane = tid & 63;
    const int l15 = lane & 15, g4 = lane >> 4;
    const int wr = w >> 1, wc = w & 1;
    const int bx = blockIdx.x, by = blockIdx.y;

    // W staging via global_load_lds (waves 4-7 -> tileId 2,3)
    const int tileId = w >> 1;
    const int halfT  = w & 1;
    const unsigned short* gsrc = (tileId == 3) ? Wl : Wh;
    const int r_l = lane >> 2, c_l = lane & 3;
    const int cs = c_l ^ (r_l & 3);
    const char* gp0 = (const char*)gsrc + (size_t)(by*128 + halfT*64 + r_l) * 2048 + cs * 16;

    // reg-staged A (all 512 threads, 8 fp32 each per K-step)
    const int arow = tid >> 2;
    const int ac   = tid & 3;
    const float* agp = A + (size_t)(bx*128 + arow) * 1024 + ac * 8;
    const int aoff = arow * 32 + ((ac ^ (arow & 3)) << 3);

    f32x4 acc[2][4];
    #pragma unroll
    for (int m = 0; m < 2; ++m)
        #pragma unroll
        for (int n = 0; n < 4; ++n) acc[m][n] = (f32x4){0.f,0.f,0.f,0.f};

    #define WSTAGE(T, BUF) do {                                             \
        const char* g_ = gp0 + (size_t)(T) * 64;                            \
        unsigned short* lb_ = &lds[BUF][tileId][halfT * 2048];              \
        gload_lds16(g_,          lb_);                                      \
        gload_lds16(g_ + 32768,  lb_ + 512);                                \
        gload_lds16(g_ + 65536,  lb_ + 1024);                               \
        gload_lds16(g_ + 98304,  lb_ + 1536);                               \
    } while (0)

    {
        float4 p0 = *(const float4*)(agp);
        float4 p1 = *(const float4*)(agp + 4);
        if (w >= 4) WSTAGE(0, 0);
        u16x8 h, l;
        split8v(p0, p1, h, l);
        *(u16x8*)&lds[0][0][aoff] = h;
        *(u16x8*)&lds[0][1][aoff] = l;
    }
    __syncthreads();

    for (int t = 0; t < 32; ++t) {
        const int cur = t & 1;
        float4 n0, n1;
        if (t < 31) {
            n0 = *(const float4*)(agp + (t+1)*32);
            n1 = *(const float4*)(agp + (t+1)*32 + 4);
            if (w >= 4) WSTAGE(t + 1, cur ^ 1);
        }
        const unsigned short* lA_h = lds[cur][0];
        const unsigned short* lA_l = lds[cur][1];
        const unsigned short* lW_h = lds[cur][2];
        const unsigned short* lW_l = lds[cur][3];
        bf16x8 ah[2], al2[2], wh4[4], wl4[4];
        #pragma unroll
        for (int m = 0; m < 2; ++m) {
            const int R = wr*32 + m*16 + l15;
            const int off = R*32 + ((g4 ^ (R & 3)) << 3);
            ah[m]  = *(const bf16x8*)(lA_h + off);
            al2[m] = *(const bf16x8*)(lA_l + off);
        }
        #pragma unroll
        for (int n = 0; n < 4; ++n) {
            const int R = wc*64 + n*16 + l15;
            const int off = R*32 + ((g4 ^ (R & 3)) << 3);
            wh4[n] = *(const bf16x8*)(lW_h + off);
            wl4[n] = *(const bf16x8*)(lW_l + off);
        }
        #pragma unroll
        for (int m = 0; m < 2; ++m)
            #pragma unroll
            for (int n = 0; n < 4; ++n) {
                acc[m][n] = __builtin_amdgcn_mfma_f32_16x16x32_bf16(ah[m],  wh4[n], acc[m][n], 0,0,0);
                acc[m][n] = __builtin_amdgcn_mfma_f32_16x16x32_bf16(ah[m],  wl4[n], acc[m][n], 0,0,0);
                acc[m][n] = __builtin_amdgcn_mfma_f32_16x16x32_bf16(al2[m], wh4[n], acc[m][n], 0,0,0);
            }
        if (t < 31) {
            u16x8 h, l;
            split8v(n0, n1, h, l);
            *(u16x8*)&lds[cur ^ 1][0][aoff] = h;
            *(u16x8*)&lds[cur ^ 1][1][aoff] = l;
        }
        __syncthreads();
    }
    #undef WSTAGE

    const int colBase = by*128 + wc*64;
    const int rowBase = bx*128 + wr*32;
    const int h = colBase >> 6;

    if (pid < 2) {      // RoPE epilogues (pid0: *QSC -> qb plain; pid1: -> kb tiled)
        unsigned short* Out = pid ? kb : qb;
        const float QSC = pid ? 1.0f : 0.125f * 1.44269504088896340736f;
        #pragma unroll
        for (int m = 0; m < 2; ++m) {
            const int srow0 = rowBase + m*16 + g4*4;
            const int b = srow0 >> 11;
            unsigned short* hb2 = Out + (size_t)(b*H_ + h) * S_ * DK;
            #pragma unroll
            for (int n = 0; n < 2; ++n) {
                const int d = n*16 + l15;
                const float invf = exp2f((float)d * -0.4152410118609203f);
                const float b1 = bias[h*64 + d], b2 = bias[h*64 + d + 32];
                #pragma unroll
                for (int r = 0; r < 4; ++r) {
                    const int s = (srow0 + r) & 2047;
                    const float x1 = acc[m][n][r]   + b1;
                    const float x2 = acc[m][n+2][r] + b2;
                    float sn, cc;
                    __sincosf((float)s * invf, &sn, &cc);
                    const float o1 = (x1*cc - x2*sn) * QSC;
                    const float o2 = (x2*cc + x1*sn) * QSC;
                    if (pid == 0) {
                        unsigned short* dst = hb2 + (size_t)s * DK;
                        dst[d]      = f2bf(o1);
                        dst[d + 32] = f2bf(o2);
                    } else {
                        unsigned short* tb = hb2 + (s >> 6) * 4096 + (s & 63) * 8;
                        tb[(d >> 3) * 512 + (d & 7)]        = f2bf(o1);
                        tb[(d >> 3) * 512 + 2048 + (d & 7)] = f2bf(o2);
                    }
                }
            }
        }
    } else {            // vt TILED
        #pragma unroll
        for (int m = 0; m < 2; ++m) {
            const int srow0 = rowBase + m*16 + g4*4;
            const int b = srow0 >> 11, s0 = srow0 & 2047;
            unsigned short* tb = vt + (size_t)(b*H_ + h) * S_ * DK
                               + (s0 >> 6) * 4096 + ((s0 & 63) >> 3) * 512 + (s0 & 7);
            #pragma unroll
            for (int n = 0; n < 4; ++n) {
                const int d = n*16 + l15;
                const float bb = bias[h*64 + d];
                u16x4 pk;
                #pragma unroll
                for (int r = 0; r < 4; ++r) pk[r] = f2bf(acc[m][n][r] + bb);
                *(u16x4*)(tb + d * 8) = pk;
            }
        }
    }
}

// ---------------------------------------------------------------------------
// Split-bf16 MFMA GEMM (pre-split A; used for the output projection).
// ---------------------------------------------------------------------------
__global__ __launch_bounds__(512) void mfma_gemm0(
    const unsigned short* __restrict__ Ah, const unsigned short* __restrict__ Al,
    const unsigned short* __restrict__ Wh, const unsigned short* __restrict__ Wl,
    const float* __restrict__ bias, float* __restrict__ Out)
{
    __shared__ __align__(16) unsigned short lds[2][4][4096];
    const int tid = threadIdx.x;
    const int w = tid >> 6, lane = tid & 63;
    const int l15 = lane & 15, g4 = lane >> 4;
    const int wr = w >> 1, wc = w & 1;
    const int bx = blockIdx.x, by = blockIdx.y;

    const int tileId = w >> 1;
    const int halfT  = w & 1;
    const unsigned short* gsrc = (tileId==0) ? Ah : (tileId==1) ? Al : (tileId==2) ? Wh : Wl;
    const int row0 = (tileId < 2) ? bx * 128 : by * 128;
    const int r_l = lane >> 2, c_l = lane & 3;
    const int cs = c_l ^ (r_l & 3);
    const char* gp0 = (const char*)gsrc + (size_t)(row0 + halfT*64 + r_l) * 2048 + cs * 16;

    f32x4 acc[2][4];
    #pragma unroll
    for (int m = 0; m < 2; ++m)
        #pragma unroll
        for (int n = 0; n < 4; ++n) acc[m][n] = (f32x4){0.f,0.f,0.f,0.f};

    #define STAGE(T, BUF) do {                                              \
        const char* g_ = gp0 + (size_t)(T) * 64;                            \
        unsigned short* lb_ = &lds[BUF][tileId][halfT * 2048];              \
        gload_lds16(g_,          lb_);                                      \
        gload_lds16(g_ + 32768,  lb_ + 512);                                \
        gload_lds16(g_ + 65536,  lb_ + 1024);                               \
        gload_lds16(g_ + 98304,  lb_ + 1536);                               \
    } while (0)

    STAGE(0, 0);
    __syncthreads();

    for (int t = 0; t < 32; ++t) {
        const int cur = t & 1;
        if (t < 31) STAGE(t + 1, cur ^ 1);
        const unsigned short* lA_h = lds[cur][0];
        const unsigned short* lA_l = lds[cur][1];
        const unsigned short* lW_h = lds[cur][2];
        const unsigned short* lW_l = lds[cur][3];
        bf16x8 ah[2], al2[2], wh4[4], wl4[4];
        #pragma unroll
        for (int m = 0; m < 2; ++m) {
            const int R = wr*32 + m*16 + l15;
            const int off = R*32 + ((g4 ^ (R & 3)) << 3);
            ah[m]  = *(const bf16x8*)(lA_h + off);
            al2[m] = *(const bf16x8*)(lA_l + off);
        }
        #pragma unroll
        for (int n = 0; n < 4; ++n) {
            const int R = wc*64 + n*16 + l15;
            const int off = R*32 + ((g4 ^ (R & 3)) << 3);
            wh4[n] = *(const bf16x8*)(lW_h + off);
            wl4[n] = *(const bf16x8*)(lW_l + off);
        }
        #pragma unroll
        for (int m = 0; m < 2; ++m)
            #pragma unroll
            for (int n = 0; n < 4; ++n) {
                acc[m][n] = __builtin_amdgcn_mfma_f32_16x16x32_bf16(ah[m],  wh4[n], acc[m][n], 0,0,0);
                acc[m][n] = __builtin_amdgcn_mfma_f32_16x16x32_bf16(ah[m],  wl4[n], acc[m][n], 0,0,0);
                acc[m][n] = __builtin_amdgcn_mfma_f32_16x16x32_bf16(al2[m], wh4[n], acc[m][n], 0,0,0);
            }
        __syncthreads();
    }
    #undef STAGE

    const int colBase = by*128 + wc*64;
    const int rowBase = bx*128 + wr*32;
    #pragma unroll
    for (int m = 0; m < 2; ++m) {
        const int row = rowBase + m*16 + g4*4;
        #pragma unroll
        for (int n = 0; n < 4; ++n) {
            const int col = colBase + n*16 + l15;
            const float bb = bias[col];
            #pragma unroll
            for (int r = 0; r < 4; ++r)
                Out[(size_t)(row + r) * 1024 + col] = acc[m][n][r] + bb;
        }
    }
}

// ---------------------------------------------------------------------------
// 32x32-MFMA flash attention. 8 waves x 32 q; grid 256; KVBLK=128; register
// softmax (no max-tracking, bounded scores); pre-tiled conflict-free K/V;
// P-exchange via v_permlane32_swap_b32 (1 VALU op fills 2 frag words).
// XCD-grouped bh. LDS: 2 bufs x (K 16K | V 16K) = 64 KB.
// ---------------------------------------------------------------------------
__global__ __launch_bounds__(512, 1) void attn_mfma7(
    const unsigned short* __restrict__ Qb, const unsigned short* __restrict__ Kb,
    const unsigned short* __restrict__ Vt,
    unsigned short* __restrict__ Xh, unsigned short* __restrict__ Xl)
{
    __shared__ __align__(16) char lds[65536];
    const unsigned bid = blockIdx.x;             // 256 blocks
    const int xcd = bid & 7, idx = bid >> 3;
    const int bh  = xcd * 4 + (idx >> 3);
    const int qt  = idx & 7;
    const int tid = threadIdx.x;
    const int w = tid >> 6, lane = tid & 63;
    const int l31 = lane & 31, hi = lane >> 5;
    const size_t bhO = (size_t)bh * S_ * DK;
    const int q0 = qt * 256 + w * 32;

    const int u0   = w * 4;
    const int isV  = u0 >> 4;
    const int u15  = u0 & 15;
    const int su0  = u15 >> 3;
    const unsigned short* sb = (isV ? Vt : Kb) + bhO;
    const int ch0 = u15 & 7;
    char* const dbase = lds;

    bf16x8 qf[4];
    #pragma unroll
    for (int ks = 0; ks < 4; ++ks)
        qf[ks] = *(const bf16x8*)(Qb + bhO + (size_t)(q0 + l31) * DK + ks*16 + hi*8);

    f32x16 oT[2];
    #pragma unroll
    for (int dh = 0; dh < 2; ++dh)
        #pragma unroll
        for (int r = 0; r < 16; ++r) oT[dh][r] = 0.f;
    float l_ = 0.f;

    #define ASTAGE(T, BUF) do {                                                     \
        const unsigned short* g_ = sb + (size_t)((T)*2 + su0) * 4096 + ch0 * 512    \
                                   + lane * 8;                                      \
        char* d_ = dbase + (BUF)*32768 + isV*16384 + su0*8192 + ch0*1024 + lane*16; \
        gload_lds16(g_,         d_);                                                \
        gload_lds16(g_ + 512,   d_ + 1024);                                         \
        gload_lds16(g_ + 1024,  d_ + 2048);                                         \
        gload_lds16(g_ + 1536,  d_ + 3072);                                         \
    } while (0)

    ASTAGE(0, 0);
    __syncthreads();

    for (int t = 0; t < 16; ++t) {
        const int cur = t & 1;
        if (t < 15) ASTAGE(t + 1, cur ^ 1);
        const char* Kl = lds + cur * 32768;
        const char* Vl = Kl + 16384;

        f32x16 s2[4];
        __builtin_amdgcn_s_setprio(1);
        #pragma unroll
        for (int kb2 = 0; kb2 < 4; ++kb2) {
            f32x16 a;
            #pragma unroll
            for (int r = 0; r < 16; ++r) a[r] = 0.f;
            const char* kbase = Kl + (kb2 >> 1) * 8192 + ((kb2 & 1) * 32 + l31) * 16;
            #pragma unroll
            for (int ks = 0; ks < 4; ++ks) {
                bf16x8 kf = *(const bf16x8*)(kbase + (ks*2 + hi) * 1024);
                a = __builtin_amdgcn_mfma_f32_32x32x16_bf16(kf, qf[ks], a, 0, 0, 0);
            }
            s2[kb2] = a;
        }
        __builtin_amdgcn_s_setprio(0);

        {
            float lsum = 0.f;
            #pragma unroll
            for (int kb2 = 0; kb2 < 4; ++kb2)
                #pragma unroll
                for (int r = 0; r < 16; ++r) {
                    const float p = EXP2(s2[kb2][r]);
                    s2[kb2][r] = p; lsum += p;
                }
            l_ += lsum;
        }

        // PV: P-frag via cvt_pk + permlane32_swap (no bpermute, no cndmask).
        // swap(a,b): a.row1 <-> b.row0  =>  a' = {lo: a, hi: b[l-32]},
        //                                   b' = {lo: a[l+32], hi: b}.
        #pragma unroll
        for (int ks2 = 0; ks2 < 8; ++ks2) {
            const int kb2 = ks2 >> 1;
            const int R0  = (ks2 & 1) * 8;
            unsigned a0 = cvtpk(s2[kb2][R0+0], s2[kb2][R0+1]);
            unsigned a1 = cvtpk(s2[kb2][R0+2], s2[kb2][R0+3]);
            unsigned b0 = cvtpk(s2[kb2][R0+4], s2[kb2][R0+5]);
            unsigned b1 = cvtpk(s2[kb2][R0+6], s2[kb2][R0+7]);
            asm("v_permlane32_swap_b32 %0, %1" : "+v"(a0), "+v"(b0));
            asm("v_permlane32_swap_b32 %0, %1" : "+v"(a1), "+v"(b1));
            union { unsigned u[4]; bf16x8 v; } pf;
            pf.u[0] = a0; pf.u[1] = a1; pf.u[2] = b0; pf.u[3] = b1;
            const char* vbase = Vl + (ks2 >> 2) * 8192 + (((ks2 & 3) * 2) + hi) * 1024;
            __builtin_amdgcn_s_setprio(1);
            #pragma unroll
            for (int dh = 0; dh < 2; ++dh) {
                bf16x8 vf = *(const bf16x8*)(vbase + (dh*32 + l31) * 16);
                oT[dh] = __builtin_amdgcn_mfma_f32_32x32x16_bf16(vf, pf.v, oT[dh], 0, 0, 0);
            }
            __builtin_amdgcn_s_setprio(0);
        }
        __syncthreads();
    }
    #undef ASTAGE

    l_ += __shfl_xor(l_, 32, 64);
    const float inv = 1.0f / l_;
    const int b = bh >> 4, h = bh & 15;
    const int q = q0 + l31;
    unsigned short* xh = Xh + (((size_t)b * S_ + q) * H_ + h) * DK;
    unsigned short* xl = Xl + (((size_t)b * S_ + q) * H_ + h) * DK;
    #pragma unroll
    for (int dh = 0; dh < 2; ++dh)
        #pragma unroll
        for (int tt = 0; tt < 4; ++tt) {
            const int dk0 = dh*32 + tt*8 + hi*4;
            u16x4 hv, lv;
            #pragma unroll
            for (int r = 0; r < 4; ++r) {
                const float o = oT[dh][tt*4 + r] * inv;
                const unsigned short hb = f2bf(o);
                hv[r] = hb;
                lv[r] = f2bf(o - bf2f(hb));
            }
            *(u16x4*)(xh + dk0) = hv;
            *(u16x4*)(xl + dk0) = lv;
        }
}

// ---------------------------------------------------------------------------
extern "C" void kernel_launch(void* const* d_in, const int* in_sizes, int n_in,
                              void* d_out, int out_size, void* d_ws, size_t ws_size,
                              hipStream_t stream)
{
    const float* query = (const float*)d_in[0];
    const float* key   = (const float*)d_in[1];
    const float* value = (const float*)d_in[2];
    const float* Wq = (const float*)d_in[3];  const float* bq = (const float*)d_in[4];
    const float* Wk = (const float*)d_in[5];  const float* bk = (const float*)d_in[6];
    const float* Wv = (const float*)d_in[7];  const float* bv = (const float*)d_in[8];
    const float* Wo = (const float*)d_in[9];  const float* bo = (const float*)d_in[10];
    float* out = (float*)d_out;

    char* ws = (char*)d_ws;
    const size_t MB = (size_t)1 << 20;
    unsigned short* Xh  = (unsigned short*)(ws + 0*MB);
    unsigned short* Xl  = (unsigned short*)(ws + 8*MB);
    unsigned short* qb  = (unsigned short*)(ws + 16*MB);
    unsigned short* vt  = (unsigned short*)(ws + 24*MB);
    unsigned short* kb  = (unsigned short*)(ws + 40*MB);
    unsigned short* wsp = (unsigned short*)(ws + 48*MB);
    unsigned short* Woh = wsp + 6291456;     unsigned short* Wol = wsp + 7340032;

    wsplit4<<<2048, 256, 0, stream>>>(Wq, Wk, Wv, Wo, wsp);

    trigemm<<<dim3(32, 8, 3), 512, 0, stream>>>(query, key, value, wsp,
                                                bq, bk, bv, qb, kb, vt);

    attn_mfma7<<<256, 512, 0, stream>>>(qb, kb, vt, Xh, Xl);

    mfma_gemm0<<<dim3(32, 8), 512, 0, stream>>>(Xh, Xl, Woh, Wol, bo, out);
}

// Round 12
// 173.583 us; speedup vs baseline: 1.2619x; 1.0020x over previous
//
#include <hip/hip_runtime.h>
#include <hip/hip_bf16.h>
#include <math.h>

// B=2, S=2048, D=1024, H=16, dk=64.
// wsplit4 -> ONE fused tri-GEMM (q/k/v projections, fused A-split + RoPE /
// tiled-V epilogues) -> 32x32-MFMA flash attention (8-wave, KVBLK=128,
// register softmax, permlane32_swap P-exchange) -> MFMA split-GEMM -> out.
//
// GEMM LDS tiles use a superrow XOR swizzle (bank-conflict-free b128 access):
//   unit(R,c) = (R>>1)*8 + (((R&1)*4+c) ^ ((R>>1)&7)),  unit = 16B, c = chunk 0..3.
// W staged via global_load_lds with linear dest + pre-permuted source (rule #21);
// A staged in-register (fp32 -> split -> ds_write at swizzled offsets).
//
// Tiled K layout per (b,h): 64-key tile t at t*4096 elems; within tile:
//   elem(key r, dk d) at chunk(d>>3)*512 + r*8 + (d&7).
// Tiled V layout per (b,h): 64-key tile t at t*4096; elem(dk dkr, key s):
//   chunk((s&63)>>3)*512 + dkr*8 + (s&7).
//
// ws (64 MB):
//  [0,8) Xh  [8,16) Xl | [16,24) qb | [24,32) vt | [40,48) kb | [48,64) W splits

#define B_ 2
#define S_ 2048
#define D_ 1024
#define H_ 16
#define DK 64

typedef __attribute__((ext_vector_type(8)))  __bf16 bf16x8;
typedef __attribute__((ext_vector_type(4)))  float  f32x4;
typedef __attribute__((ext_vector_type(16))) float  f32x16;
typedef __attribute__((ext_vector_type(8)))  unsigned short u16x8;
typedef __attribute__((ext_vector_type(4)))  unsigned short u16x4;

#if __has_builtin(__builtin_amdgcn_exp2f)
#define EXP2(x) __builtin_amdgcn_exp2f(x)
#else
#define EXP2(x) exp2f(x)
#endif

static __device__ __forceinline__ unsigned short f2bf(float x) {
    union { float f; unsigned u; } v; v.f = x;
    unsigned r = v.u + 0x7FFFu + ((v.u >> 16) & 1u);   // RNE
    return (unsigned short)(r >> 16);
}
static __device__ __forceinline__ float bf2f(unsigned short h) {
    union { unsigned u; float f; } v; v.u = ((unsigned)h) << 16;
    return v.f;
}
static __device__ __forceinline__ unsigned cvtpk(float lo, float hi) {
    unsigned r;
    asm("v_cvt_pk_bf16_f32 %0, %1, %2" : "=v"(r) : "v"(lo), "v"(hi));
    return r;
}
static __device__ __forceinline__ void gload_lds16(const void* g, void* l) {
    __builtin_amdgcn_global_load_lds(
        (const __attribute__((address_space(1))) void*)g,
        (__attribute__((address_space(3))) void*)l, 16, 0, 0);
}
static __device__ __forceinline__ void split8v(float4 a, float4 b, u16x8& h, u16x8& l) {
    float x[8] = {a.x,a.y,a.z,a.w,b.x,b.y,b.z,b.w};
    #pragma unroll
    for (int j = 0; j < 8; ++j) {
        unsigned short hb = f2bf(x[j]);
        h[j] = hb;
        l[j] = f2bf(x[j] - bf2f(hb));
    }
}
// shorts offset of logical (row R, 8-elem chunk c) in an 8KB [128][32]bf16 tile,
// superrow XOR swizzle (conflict-free b128).
static __device__ __forceinline__ int swz(int R, int c) {
    return ((R >> 1) << 6) + (((((R & 1) << 2) | c) ^ ((R >> 1) & 7)) << 3);
}

// ---------------------------------------------------------------------------
// 4-weight fp32 -> bf16 hi/lo split. out: per weight t, hi @ t*2M, lo @ +1M.
// ---------------------------------------------------------------------------
__global__ __launch_bounds__(256) void wsplit4(
    const float* __restrict__ W0, const float* __restrict__ W1,
    const float* __restrict__ W2, const float* __restrict__ W3,
    unsigned short* __restrict__ out)
{
    const int idx = blockIdx.x * 256 + threadIdx.x;
    const int t = idx >> 17;
    const size_t e = (size_t)(idx & 131071) * 8;
    const float* src = (t==0 ? W0 : t==1 ? W1 : t==2 ? W2 : W3) + e;
    unsigned short* hi = out + (size_t)t * 2097152 + e;
    unsigned short* lo = hi + 1048576;
    float4 a = *(const float4*)src;
    float4 b = *(const float4*)(src + 4);
    u16x8 h, l;
    split8v(a, b, h, l);
    *(u16x8*)hi = h;
    *(u16x8*)lo = l;
}

// ---------------------------------------------------------------------------
// Fused tri-GEMM: all three projections in one launch (blockIdx.z = problem).
// fp32 A reg-staged + split to hi/lo bf16 (swizzled ds_write); W via
// global_load_lds, linear dest + source-permuted for the swizzle.
// pid 0: RoPE*QSC -> qb (B,H,S,dk). pid 1: RoPE -> kb TILED. pid 2: vt TILED.
// ---------------------------------------------------------------------------
__global__ __launch_bounds__(512) void trigemm(
    const float* __restrict__ Aq, const float* __restrict__ Ak,
    const float* __restrict__ Av, const unsigned short* __restrict__ wsp,
    const float* __restrict__ bq, const float* __restrict__ bk,
    const float* __restrict__ bv,
    unsigned short* __restrict__ qb, unsigned short* __restrict__ kb,
    unsigned short* __restrict__ vt)
{
    __shared__ __align__(16) unsigned short lds[2][4][4096];
    const int pid = blockIdx.z;
    const float* A    = (pid==0) ? Aq : (pid==1) ? Ak : Av;
    const float* bias = (pid==0) ? bq : (pid==1) ? bk : bv;
    const unsigned short* Wh = wsp + (size_t)pid * 2097152;
    const unsigned short* Wl = Wh + 1048576;

    const int tid = threadIdx.x;
    const int w = tid >> 6, lane = tid & 63;
    const int l15 = lane & 15, g4 = lane >> 4;
    const int wr = w >> 1, wc = w & 1;
    const int bx = blockIdx.x, by = blockIdx.y;

    // W staging via global_load_lds (waves 4-7 -> tileId 2,3), source-permuted
    const int tileId = w >> 1;
    const int halfT  = w & 1;
    const unsigned short* gsrc = (tileId == 3) ? Wl : Wh;
    const int su_   = (lane & 7) ^ (lane >> 3);
    const int wrow_ = halfT * 64 + ((lane >> 3) << 1) + (su_ >> 2);
    const char* gp0 = (const char*)gsrc + (size_t)(by*128 + wrow_) * 2048 + (su_ & 3) * 16;

    // reg-staged A (all 512 threads, 8 fp32 each per K-step), swizzled ds_write
    const int arow = tid >> 2;
    const int ac   = tid & 3;
    const float* agp = A + (size_t)(bx*128 + arow) * 1024 + ac * 8;
    const int aoff = swz(arow, ac);

    f32x4 acc[2][4];
    #pragma unroll
    for (int m = 0; m < 2; ++m)
        #pragma unroll
        for (int n = 0; n < 4; ++n) acc[m][n] = (f32x4){0.f,0.f,0.f,0.f};

    #define WSTAGE(T, BUF) do {                                             \
        const char* g_ = gp0 + (size_t)(T) * 64;                            \
        unsigned short* lb_ = &lds[BUF][tileId][halfT * 2048];              \
        gload_lds16(g_,          lb_);                                      \
        gload_lds16(g_ + 32768,  lb_ + 512);                                \
        gload_lds16(g_ + 65536,  lb_ + 1024);                               \
        gload_lds16(g_ + 98304,  lb_ + 1536);                               \
    } while (0)

    {
        float4 p0 = *(const float4*)(agp);
        float4 p1 = *(const float4*)(agp + 4);
        if (w >= 4) WSTAGE(0, 0);
        u16x8 h, l;
        split8v(p0, p1, h, l);
        *(u16x8*)&lds[0][0][aoff] = h;
        *(u16x8*)&lds[0][1][aoff] = l;
    }
    __syncthreads();

    for (int t = 0; t < 32; ++t) {
        const int cur = t & 1;
        float4 n0, n1;
        if (t < 31) {
            n0 = *(const float4*)(agp + (t+1)*32);
            n1 = *(const float4*)(agp + (t+1)*32 + 4);
            if (w >= 4) WSTAGE(t + 1, cur ^ 1);
        }
        const unsigned short* lA_h = lds[cur][0];
        const unsigned short* lA_l = lds[cur][1];
        const unsigned short* lW_h = lds[cur][2];
        const unsigned short* lW_l = lds[cur][3];
        bf16x8 ah[2], al2[2], wh4[4], wl4[4];
        #pragma unroll
        for (int m = 0; m < 2; ++m) {
            const int off = swz(wr*32 + m*16 + l15, g4);
            ah[m]  = *(const bf16x8*)(lA_h + off);
            al2[m] = *(const bf16x8*)(lA_l + off);
        }
        #pragma unroll
        for (int n = 0; n < 4; ++n) {
            const int off = swz(wc*64 + n*16 + l15, g4);
            wh4[n] = *(const bf16x8*)(lW_h + off);
            wl4[n] = *(const bf16x8*)(lW_l + off);
        }
        #pragma unroll
        for (int m = 0; m < 2; ++m)
            #pragma unroll
            for (int n = 0; n < 4; ++n) {
                acc[m][n] = __builtin_amdgcn_mfma_f32_16x16x32_bf16(ah[m],  wh4[n], acc[m][n], 0,0,0);
                acc[m][n] = __builtin_amdgcn_mfma_f32_16x16x32_bf16(ah[m],  wl4[n], acc[m][n], 0,0,0);
                acc[m][n] = __builtin_amdgcn_mfma_f32_16x16x32_bf16(al2[m], wh4[n], acc[m][n], 0,0,0);
            }
        if (t < 31) {
            u16x8 h, l;
            split8v(n0, n1, h, l);
            *(u16x8*)&lds[cur ^ 1][0][aoff] = h;
            *(u16x8*)&lds[cur ^ 1][1][aoff] = l;
        }
        __syncthreads();
    }
    #undef WSTAGE

    const int colBase = by*128 + wc*64;
    const int rowBase = bx*128 + wr*32;
    const int h = colBase >> 6;

    if (pid < 2) {      // RoPE epilogues (pid0: *QSC -> qb plain; pid1: -> kb tiled)
        unsigned short* Out = pid ? kb : qb;
        const float QSC = pid ? 1.0f : 0.125f * 1.44269504088896340736f;
        #pragma unroll
        for (int m = 0; m < 2; ++m) {
            const int srow0 = rowBase + m*16 + g4*4;
            const int b = srow0 >> 11;
            unsigned short* hb2 = Out + (size_t)(b*H_ + h) * S_ * DK;
            #pragma unroll
            for (int n = 0; n < 2; ++n) {
                const int d = n*16 + l15;
                const float invf = exp2f((float)d * -0.4152410118609203f);
                const float b1 = bias[h*64 + d], b2 = bias[h*64 + d + 32];
                #pragma unroll
                for (int r = 0; r < 4; ++r) {
                    const int s = (srow0 + r) & 2047;
                    const float x1 = acc[m][n][r]   + b1;
                    const float x2 = acc[m][n+2][r] + b2;
                    float sn, cc;
                    __sincosf((float)s * invf, &sn, &cc);
                    const float o1 = (x1*cc - x2*sn) * QSC;
                    const float o2 = (x2*cc + x1*sn) * QSC;
                    if (pid == 0) {
                        unsigned short* dst = hb2 + (size_t)s * DK;
                        dst[d]      = f2bf(o1);
                        dst[d + 32] = f2bf(o2);
                    } else {
                        unsigned short* tb = hb2 + (s >> 6) * 4096 + (s & 63) * 8;
                        tb[(d >> 3) * 512 + (d & 7)]        = f2bf(o1);
                        tb[(d >> 3) * 512 + 2048 + (d & 7)] = f2bf(o2);
                    }
                }
            }
        }
    } else {            // vt TILED
        #pragma unroll
        for (int m = 0; m < 2; ++m) {
            const int srow0 = rowBase + m*16 + g4*4;
            const int b = srow0 >> 11, s0 = srow0 & 2047;
            unsigned short* tb = vt + (size_t)(b*H_ + h) * S_ * DK
                               + (s0 >> 6) * 4096 + ((s0 & 63) >> 3) * 512 + (s0 & 7);
            #pragma unroll
            for (int n = 0; n < 4; ++n) {
                const int d = n*16 + l15;
                const float bb = bias[h*64 + d];
                u16x4 pk;
                #pragma unroll
                for (int r = 0; r < 4; ++r) pk[r] = f2bf(acc[m][n][r] + bb);
                *(u16x4*)(tb + d * 8) = pk;
            }
        }
    }
}

// ---------------------------------------------------------------------------
// Split-bf16 MFMA GEMM (pre-split A via gload; output projection).
// Same superrow-swizzled LDS scheme.
// ---------------------------------------------------------------------------
__global__ __launch_bounds__(512) void mfma_gemm0(
    const unsigned short* __restrict__ Ah, const unsigned short* __restrict__ Al,
    const unsigned short* __restrict__ Wh, const unsigned short* __restrict__ Wl,
    const float* __restrict__ bias, float* __restrict__ Out)
{
    __shared__ __align__(16) unsigned short lds[2][4][4096];
    const int tid = threadIdx.x;
    const int w = tid >> 6, lane = tid & 63;
    const int l15 = lane & 15, g4 = lane >> 4;
    const int wr = w >> 1, wc = w & 1;
    const int bx = blockIdx.x, by = blockIdx.y;

    const int tileId = w >> 1;
    const int halfT  = w & 1;
    const unsigned short* gsrc = (tileId==0) ? Ah : (tileId==1) ? Al : (tileId==2) ? Wh : Wl;
    const int row0 = (tileId < 2) ? bx * 128 : by * 128;
    const int su_   = (lane & 7) ^ (lane >> 3);
    const int wrow_ = halfT * 64 + ((lane >> 3) << 1) + (su_ >> 2);
    const char* gp0 = (const char*)gsrc + (size_t)(row0 + wrow_) * 2048 + (su_ & 3) * 16;

    f32x4 acc[2][4];
    #pragma unroll
    for (int m = 0; m < 2; ++m)
        #pragma unroll
        for (int n = 0; n < 4; ++n) acc[m][n] = (f32x4){0.f,0.f,0.f,0.f};

    #define STAGE(T, BUF) do {                                              \
        const char* g_ = gp0 + (size_t)(T) * 64;                            \
        unsigned short* lb_ = &lds[BUF][tileId][halfT * 2048];              \
        gload_lds16(g_,          lb_);                                      \
        gload_lds16(g_ + 32768,  lb_ + 512);                                \
        gload_lds16(g_ + 65536,  lb_ + 1024);                               \
        gload_lds16(g_ + 98304,  lb_ + 1536);                               \
    } while (0)

    STAGE(0, 0);
    __syncthreads();

    for (int t = 0; t < 32; ++t) {
        const int cur = t & 1;
        if (t < 31) STAGE(t + 1, cur ^ 1);
        const unsigned short* lA_h = lds[cur][0];
        const unsigned short* lA_l = lds[cur][1];
        const unsigned short* lW_h = lds[cur][2];
        const unsigned short* lW_l = lds[cur][3];
        bf16x8 ah[2], al2[2], wh4[4], wl4[4];
        #pragma unroll
        for (int m = 0; m < 2; ++m) {
            const int off = swz(wr*32 + m*16 + l15, g4);
            ah[m]  = *(const bf16x8*)(lA_h + off);
            al2[m] = *(const bf16x8*)(lA_l + off);
        }
        #pragma unroll
        for (int n = 0; n < 4; ++n) {
            const int off = swz(wc*64 + n*16 + l15, g4);
            wh4[n] = *(const bf16x8*)(lW_h + off);
            wl4[n] = *(const bf16x8*)(lW_l + off);
        }
        #pragma unroll
        for (int m = 0; m < 2; ++m)
            #pragma unroll
            for (int n = 0; n < 4; ++n) {
                acc[m][n] = __builtin_amdgcn_mfma_f32_16x16x32_bf16(ah[m],  wh4[n], acc[m][n], 0,0,0);
                acc[m][n] = __builtin_amdgcn_mfma_f32_16x16x32_bf16(ah[m],  wl4[n], acc[m][n], 0,0,0);
                acc[m][n] = __builtin_amdgcn_mfma_f32_16x16x32_bf16(al2[m], wh4[n], acc[m][n], 0,0,0);
            }
        __syncthreads();
    }
    #undef STAGE

    const int colBase = by*128 + wc*64;
    const int rowBase = bx*128 + wr*32;
    #pragma unroll
    for (int m = 0; m < 2; ++m) {
        const int row = rowBase + m*16 + g4*4;
        #pragma unroll
        for (int n = 0; n < 4; ++n) {
            const int col = colBase + n*16 + l15;
            const float bb = bias[col];
            #pragma unroll
            for (int r = 0; r < 4; ++r)
                Out[(size_t)(row + r) * 1024 + col] = acc[m][n][r] + bb;
        }
    }
}

// ---------------------------------------------------------------------------
// 32x32-MFMA flash attention (unchanged from round 11).
// ---------------------------------------------------------------------------
__global__ __launch_bounds__(512, 1) void attn_mfma7(
    const unsigned short* __restrict__ Qb, const unsigned short* __restrict__ Kb,
    const unsigned short* __restrict__ Vt,
    unsigned short* __restrict__ Xh, unsigned short* __restrict__ Xl)
{
    __shared__ __align__(16) char lds[65536];
    const unsigned bid = blockIdx.x;             // 256 blocks
    const int xcd = bid & 7, idx = bid >> 3;
    const int bh  = xcd * 4 + (idx >> 3);
    const int qt  = idx & 7;
    const int tid = threadIdx.x;
    const int w = tid >> 6, lane = tid & 63;
    const int l31 = lane & 31, hi = lane >> 5;
    const size_t bhO = (size_t)bh * S_ * DK;
    const int q0 = qt * 256 + w * 32;

    const int u0   = w * 4;
    const int isV  = u0 >> 4;
    const int u15  = u0 & 15;
    const int su0  = u15 >> 3;
    const unsigned short* sb = (isV ? Vt : Kb) + bhO;
    const int ch0 = u15 & 7;
    char* const dbase = lds;

    bf16x8 qf[4];
    #pragma unroll
    for (int ks = 0; ks < 4; ++ks)
        qf[ks] = *(const bf16x8*)(Qb + bhO + (size_t)(q0 + l31) * DK + ks*16 + hi*8);

    f32x16 oT[2];
    #pragma unroll
    for (int dh = 0; dh < 2; ++dh)
        #pragma unroll
        for (int r = 0; r < 16; ++r) oT[dh][r] = 0.f;
    float l_ = 0.f;

    #define ASTAGE(T, BUF) do {                                                     \
        const unsigned short* g_ = sb + (size_t)((T)*2 + su0) * 4096 + ch0 * 512    \
                                   + lane * 8;                                      \
        char* d_ = dbase + (BUF)*32768 + isV*16384 + su0*8192 + ch0*1024 + lane*16; \
        gload_lds16(g_,         d_);                                                \
        gload_lds16(g_ + 512,   d_ + 1024);                                         \
        gload_lds16(g_ + 1024,  d_ + 2048);                                         \
        gload_lds16(g_ + 1536,  d_ + 3072);                                         \
    } while (0)

    ASTAGE(0, 0);
    __syncthreads();

    for (int t = 0; t < 16; ++t) {
        const int cur = t & 1;
        if (t < 15) ASTAGE(t + 1, cur ^ 1);
        const char* Kl = lds + cur * 32768;
        const char* Vl = Kl + 16384;

        f32x16 s2[4];
        __builtin_amdgcn_s_setprio(1);
        #pragma unroll
        for (int kb2 = 0; kb2 < 4; ++kb2) {
            f32x16 a;
            #pragma unroll
            for (int r = 0; r < 16; ++r) a[r] = 0.f;
            const char* kbase = Kl + (kb2 >> 1) * 8192 + ((kb2 & 1) * 32 + l31) * 16;
            #pragma unroll
            for (int ks = 0; ks < 4; ++ks) {
                bf16x8 kf = *(const bf16x8*)(kbase + (ks*2 + hi) * 1024);
                a = __builtin_amdgcn_mfma_f32_32x32x16_bf16(kf, qf[ks], a, 0, 0, 0);
            }
            s2[kb2] = a;
        }
        __builtin_amdgcn_s_setprio(0);

        {
            float lsum = 0.f;
            #pragma unroll
            for (int kb2 = 0; kb2 < 4; ++kb2)
                #pragma unroll
                for (int r = 0; r < 16; ++r) {
                    const float p = EXP2(s2[kb2][r]);
                    s2[kb2][r] = p; lsum += p;
                }
            l_ += lsum;
        }

        // PV: P-frag via cvt_pk + permlane32_swap.
        #pragma unroll
        for (int ks2 = 0; ks2 < 8; ++ks2) {
            const int kb2 = ks2 >> 1;
            const int R0  = (ks2 & 1) * 8;
            unsigned a0 = cvtpk(s2[kb2][R0+0], s2[kb2][R0+1]);
            unsigned a1 = cvtpk(s2[kb2][R0+2], s2[kb2][R0+3]);
            unsigned b0 = cvtpk(s2[kb2][R0+4], s2[kb2][R0+5]);
            unsigned b1 = cvtpk(s2[kb2][R0+6], s2[kb2][R0+7]);
            asm("v_permlane32_swap_b32 %0, %1" : "+v"(a0), "+v"(b0));
            asm("v_permlane32_swap_b32 %0, %1" : "+v"(a1), "+v"(b1));
            union { unsigned u[4]; bf16x8 v; } pf;
            pf.u[0] = a0; pf.u[1] = a1; pf.u[2] = b0; pf.u[3] = b1;
            const char* vbase = Vl + (ks2 >> 2) * 8192 + (((ks2 & 3) * 2) + hi) * 1024;
            __builtin_amdgcn_s_setprio(1);
            #pragma unroll
            for (int dh = 0; dh < 2; ++dh) {
                bf16x8 vf = *(const bf16x8*)(vbase + (dh*32 + l31) * 16);
                oT[dh] = __builtin_amdgcn_mfma_f32_32x32x16_bf16(vf, pf.v, oT[dh], 0, 0, 0);
            }
            __builtin_amdgcn_s_setprio(0);
        }
        __syncthreads();
    }
    #undef ASTAGE

    l_ += __shfl_xor(l_, 32, 64);
    const float inv = 1.0f / l_;
    const int b = bh >> 4, h = bh & 15;
    const int q = q0 + l31;
    unsigned short* xh = Xh + (((size_t)b * S_ + q) * H_ + h) * DK;
    unsigned short* xl = Xl + (((size_t)b * S_ + q) * H_ + h) * DK;
    #pragma unroll
    for (int dh = 0; dh < 2; ++dh)
        #pragma unroll
        for (int tt = 0; tt < 4; ++tt) {
            const int dk0 = dh*32 + tt*8 + hi*4;
            u16x4 hv, lv;
            #pragma unroll
            for (int r = 0; r < 4; ++r) {
                const float o = oT[dh][tt*4 + r] * inv;
                const unsigned short hb = f2bf(o);
                hv[r] = hb;
                lv[r] = f2bf(o - bf2f(hb));
            }
            *(u16x4*)(xh + dk0) = hv;
            *(u16x4*)(xl + dk0) = lv;
        }
}

// ---------------------------------------------------------------------------
extern "C" void kernel_launch(void* const* d_in, const int* in_sizes, int n_in,
                              void* d_out, int out_size, void* d_ws, size_t ws_size,
                              hipStream_t stream)
{
    const float* query = (const float*)d_in[0];
    const float* key   = (const float*)d_in[1];
    const float* value = (const float*)d_in[2];
    const float* Wq = (const float*)d_in[3];  const float* bq = (const float*)d_in[4];
    const float* Wk = (const float*)d_in[5];  const float* bk = (const float*)d_in[6];
    const float* Wv = (const float*)d_in[7];  const float* bv = (const float*)d_in[8];
    const float* Wo = (const float*)d_in[9];  const float* bo = (const float*)d_in[10];
    float* out = (float*)d_out;

    char* ws = (char*)d_ws;
    const size_t MB = (size_t)1 << 20;
    unsigned short* Xh  = (unsigned short*)(ws + 0*MB);
    unsigned short* Xl  = (unsigned short*)(ws + 8*MB);
    unsigned short* qb  = (unsigned short*)(ws + 16*MB);
    unsigned short* vt  = (unsigned short*)(ws + 24*MB);
    unsigned short* kb  = (unsigned short*)(ws + 40*MB);
    unsigned short* wsp = (unsigned short*)(ws + 48*MB);
    unsigned short* Woh = wsp + 6291456;     unsigned short* Wol = wsp + 7340032;

    wsplit4<<<2048, 256, 0, stream>>>(Wq, Wk, Wv, Wo, wsp);

    trigemm<<<dim3(32, 8, 3), 512, 0, stream>>>(query, key, value, wsp,
                                                bq, bk, bv, qb, kb, vt);

    attn_mfma7<<<256, 512, 0, stream>>>(qb, kb, vt, Xh, Xl);

    mfma_gemm0<<<dim3(32, 8), 512, 0, stream>>>(Xh, Xl, Woh, Wol, bo, out);
}

// Round 13
// 168.922 us; speedup vs baseline: 1.2967x; 1.0276x over previous
//
#include <hip/hip_runtime.h>
#include <hip/hip_bf16.h>
#include <math.h>

// B=2, S=2048, D=1024, H=16, dk=64.
// wsplit4 -> ONE fused tri-GEMM (q/k/v projections; A staged as RAW FP32 via
// global_load_lds, hi/lo split done in-register with v_cvt_pk_bf16_f32 at
// fragment-read time; fused RoPE / tiled-V epilogues) -> 32x32-MFMA flash
// attention (8-wave, KVBLK=128, register softmax, permlane32_swap) ->
// MFMA split-GEMM -> out.
//
// trigemm LDS per buf (32KB x 2): A fp32 tile 16KB | Wh 8KB | Wl 8KB.
//  A tile: 128 rows x 32 fp32; 16B chunk (R,c), c=0..7: linear u = R*8 + (c^(R&7)).
//  W tiles: [128][32] bf16, unit u16-offset swz(R,c) (superrow XOR, round 12).
// All staging via global_load_lds: linear dest + pre-permuted per-lane source.
//
// Tiled K layout per (b,h): 64-key tile t at t*4096 elems; within tile:
//   elem(key r, dk d) at chunk(d>>3)*512 + r*8 + (d&7).
// Tiled V layout per (b,h): 64-key tile t at t*4096; elem(dk dkr, key s):
//   chunk((s&63)>>3)*512 + dkr*8 + (s&7).
//
// ws (64 MB):
//  [0,8) Xh  [8,16) Xl | [16,24) qb | [24,32) vt | [40,48) kb | [48,64) W splits

#define B_ 2
#define S_ 2048
#define D_ 1024
#define H_ 16
#define DK 64

typedef __attribute__((ext_vector_type(8)))  __bf16 bf16x8;
typedef __attribute__((ext_vector_type(4)))  float  f32x4;
typedef __attribute__((ext_vector_type(16))) float  f32x16;
typedef __attribute__((ext_vector_type(8)))  unsigned short u16x8;
typedef __attribute__((ext_vector_type(4)))  unsigned short u16x4;

#if __has_builtin(__builtin_amdgcn_exp2f)
#define EXP2(x) __builtin_amdgcn_exp2f(x)
#else
#define EXP2(x) exp2f(x)
#endif

static __device__ __forceinline__ unsigned short f2bf(float x) {
    union { float f; unsigned u; } v; v.f = x;
    unsigned r = v.u + 0x7FFFu + ((v.u >> 16) & 1u);   // RNE
    return (unsigned short)(r >> 16);
}
static __device__ __forceinline__ float bf2f(unsigned short h) {
    union { unsigned u; float f; } v; v.u = ((unsigned)h) << 16;
    return v.f;
}
static __device__ __forceinline__ unsigned cvtpk(float lo, float hi) {
    unsigned r;
    asm("v_cvt_pk_bf16_f32 %0, %1, %2" : "=v"(r) : "v"(lo), "v"(hi));
    return r;
}
static __device__ __forceinline__ void gload_lds16(const void* g, void* l) {
    __builtin_amdgcn_global_load_lds(
        (const __attribute__((address_space(1))) void*)g,
        (__attribute__((address_space(3))) void*)l, 16, 0, 0);
}
// shorts offset of logical (row R, 8-elem chunk c) in an 8KB [128][32]bf16 tile.
static __device__ __forceinline__ int swz(int R, int c) {
    return ((R >> 1) << 6) + (((((R & 1) << 2) | c) ^ ((R >> 1) & 7)) << 3);
}
union bfrag { unsigned u[4]; bf16x8 v; };
// split 2 fp32 -> one hi dword + one lo dword (bf16 pairs), RNE, self-correcting.
static __device__ __forceinline__ void splitpk(float e0, float e1,
                                               unsigned& hd, unsigned& ld) {
    hd = cvtpk(e0, e1);
    union { unsigned u; float f; } flo, fhi;
    flo.u = hd << 16; fhi.u = hd & 0xFFFF0000u;
    ld = cvtpk(e0 - flo.f, e1 - fhi.f);
}

// ---------------------------------------------------------------------------
// 4-weight fp32 -> bf16 hi/lo split (cvtpk). per weight t: hi @ t*2M, lo @ +1M.
// ---------------------------------------------------------------------------
__global__ __launch_bounds__(256) void wsplit4(
    const float* __restrict__ W0, const float* __restrict__ W1,
    const float* __restrict__ W2, const float* __restrict__ W3,
    unsigned short* __restrict__ out)
{
    const int idx = blockIdx.x * 256 + threadIdx.x;
    const int t = idx >> 17;
    const size_t e = (size_t)(idx & 131071) * 8;
    const float* src = (t==0 ? W0 : t==1 ? W1 : t==2 ? W2 : W3) + e;
    unsigned short* hi = out + (size_t)t * 2097152 + e;
    unsigned short* lo = hi + 1048576;
    float4 a = *(const float4*)src;
    float4 b = *(const float4*)(src + 4);
    float x[8] = {a.x,a.y,a.z,a.w,b.x,b.y,b.z,b.w};
    union { unsigned u[4]; u16x8 v; } H, L;
    #pragma unroll
    for (int j = 0; j < 4; ++j) splitpk(x[2*j], x[2*j+1], H.u[j], L.u[j]);
    *(u16x8*)hi = H.v;
    *(u16x8*)lo = L.v;
}

// ---------------------------------------------------------------------------
// Fused tri-GEMM (blockIdx.z = problem). A staged as fp32 via global_load_lds
// (waves 0-3); W hi/lo via global_load_lds (waves 4-7). A split to bf16 hi/lo
// IN REGISTER (cvtpk) at fragment-read time. One barrier per K-step.
// pid 0: RoPE*QSC -> qb (B,H,S,dk). pid 1: RoPE -> kb TILED. pid 2: vt TILED.
// ---------------------------------------------------------------------------
__global__ __launch_bounds__(512) void trigemm(
    const float* __restrict__ Aq, const float* __restrict__ Ak,
    const float* __restrict__ Av, const unsigned short* __restrict__ wsp,
    const float* __restrict__ bq, const float* __restrict__ bk,
    const float* __restrict__ bv,
    unsigned short* __restrict__ qb, unsigned short* __restrict__ kb,
    unsigned short* __restrict__ vt)
{
    __shared__ __align__(16) char ldsb[65536];   // 2 bufs x (A 16K | Wh 8K | Wl 8K)
    const int pid = blockIdx.z;
    const float* A    = (pid==0) ? Aq : (pid==1) ? Ak : Av;
    const float* bias = (pid==0) ? bq : (pid==1) ? bk : bv;

    const int tid = threadIdx.x;
    const int w = tid >> 6, lane = tid & 63;
    const int l15 = lane & 15, g4 = lane >> 4;
    const int wr = w >> 1, wc = w & 1;
    const int bx = blockIdx.x, by = blockIdx.y;

    // ---- staging geometry (per-lane permuted sources, linear LDS dests) ----
    const int lr8 = lane >> 3;               // 0..7
    const int zz  = (lane & 7) ^ lr8;        // permuted slot
    // A (waves 0-3): lane covers row w*32 + j*8 + lr8, fp32 chunk zz (16B)
    const float* gpA = A + (size_t)(bx*128 + w*32 + lr8) * 1024 + zz * 4;
    // W (waves 4-7): p = w-4; tensor tp = p>>1 (0=Wh,1=Wl); q = p&1
    const int p_ = w - 4, tp = (p_ >> 1) & 1, qq = p_ & 1;
    const unsigned short* Wbase = wsp + (size_t)pid * 2097152 + (size_t)tp * 1048576;
    const int wR0 = qq*64 + (lr8 << 1) + (zz >> 2);
    const unsigned short* gpW = Wbase + (size_t)(by*128 + wR0) * 1024 + (zz & 3) * 8;

    f32x4 acc[2][4];
    #pragma unroll
    for (int m = 0; m < 2; ++m)
        #pragma unroll
        for (int n = 0; n < 4; ++n) acc[m][n] = (f32x4){0.f,0.f,0.f,0.f};

    #define STAGE(T, BUF) do {                                               \
        if (w < 4) {                                                         \
            const float* g_ = gpA + (size_t)(T) * 32;                        \
            char* d_ = ldsb + (BUF)*32768 + w*4096;                          \
            gload_lds16(g_,          d_);                                    \
            gload_lds16(g_ + 8192,   d_ + 1024);                             \
            gload_lds16(g_ + 16384,  d_ + 2048);                             \
            gload_lds16(g_ + 24576,  d_ + 3072);                             \
        } else {                                                             \
            const unsigned short* g_ = gpW + (size_t)(T) * 32;               \
            char* d_ = ldsb + (BUF)*32768 + 16384 + tp*8192 + qq*4096;       \
            gload_lds16(g_,          d_);                                    \
            gload_lds16(g_ + 16384,  d_ + 1024);                             \
            gload_lds16(g_ + 32768,  d_ + 2048);                             \
            gload_lds16(g_ + 49152,  d_ + 3072);                             \
        }                                                                    \
    } while (0)

    STAGE(0, 0);
    __syncthreads();

    for (int t = 0; t < 32; ++t) {
        const int cur = t & 1;
        if (t < 31) STAGE(t + 1, cur ^ 1);
        const char* Abuf = ldsb + cur * 32768;
        const unsigned short* Whb = (const unsigned short*)(Abuf + 16384);
        const unsigned short* Wlb = Whb + 4096;

        // ---- A frags: read fp32 from LDS, split hi/lo in-register ----
        bfrag ah[2], al[2];
        #pragma unroll
        for (int m = 0; m < 2; ++m) {
            const int R = wr*32 + m*16 + l15;
            const int b8 = R * 8, r7 = R & 7;
            f32x4 x0 = *(const f32x4*)(Abuf + (size_t)(b8 + ((g4*2)     ^ r7)) * 16);
            f32x4 x1 = *(const f32x4*)(Abuf + (size_t)(b8 + ((g4*2 + 1) ^ r7)) * 16);
            float e[8] = {x0[0],x0[1],x0[2],x0[3],x1[0],x1[1],x1[2],x1[3]};
            #pragma unroll
            for (int j = 0; j < 4; ++j)
                splitpk(e[2*j], e[2*j+1], ah[m].u[j], al[m].u[j]);
        }
        // ---- W frags (pre-split, swizzled) ----
        bf16x8 wh4[4], wl4[4];
        #pragma unroll
        for (int n = 0; n < 4; ++n) {
            const int off = swz(wc*64 + n*16 + l15, g4);
            wh4[n] = *(const bf16x8*)(Whb + off);
            wl4[n] = *(const bf16x8*)(Wlb + off);
        }
        #pragma unroll
        for (int m = 0; m < 2; ++m)
            #pragma unroll
            for (int n = 0; n < 4; ++n) {
                acc[m][n] = __builtin_amdgcn_mfma_f32_16x16x32_bf16(ah[m].v, wh4[n], acc[m][n], 0,0,0);
                acc[m][n] = __builtin_amdgcn_mfma_f32_16x16x32_bf16(ah[m].v, wl4[n], acc[m][n], 0,0,0);
                acc[m][n] = __builtin_amdgcn_mfma_f32_16x16x32_bf16(al[m].v, wh4[n], acc[m][n], 0,0,0);
            }
        __syncthreads();
    }
    #undef STAGE

    const int colBase = by*128 + wc*64;
    const int rowBase = bx*128 + wr*32;
    const int h = colBase >> 6;

    if (pid < 2) {      // RoPE epilogues (pid0: *QSC -> qb plain; pid1: -> kb tiled)
        unsigned short* Out = pid ? kb : qb;
        const float QSC = pid ? 1.0f : 0.125f * 1.44269504088896340736f;
        #pragma unroll
        for (int m = 0; m < 2; ++m) {
            const int srow0 = rowBase + m*16 + g4*4;
            const int b = srow0 >> 11;
            unsigned short* hb2 = Out + (size_t)(b*H_ + h) * S_ * DK;
            #pragma unroll
            for (int n = 0; n < 2; ++n) {
                const int d = n*16 + l15;
                const float invf = exp2f((float)d * -0.4152410118609203f);
                const float b1 = bias[h*64 + d], b2 = bias[h*64 + d + 32];
                #pragma unroll
                for (int r = 0; r < 4; ++r) {
                    const int s = (srow0 + r) & 2047;
                    const float x1 = acc[m][n][r]   + b1;
                    const float x2 = acc[m][n+2][r] + b2;
                    float sn, cc;
                    __sincosf((float)s * invf, &sn, &cc);
                    const float o1 = (x1*cc - x2*sn) * QSC;
                    const float o2 = (x2*cc + x1*sn) * QSC;
                    if (pid == 0) {
                        unsigned short* dst = hb2 + (size_t)s * DK;
                        dst[d]      = f2bf(o1);
                        dst[d + 32] = f2bf(o2);
                    } else {
                        unsigned short* tb = hb2 + (s >> 6) * 4096 + (s & 63) * 8;
                        tb[(d >> 3) * 512 + (d & 7)]        = f2bf(o1);
                        tb[(d >> 3) * 512 + 2048 + (d & 7)] = f2bf(o2);
                    }
                }
            }
        }
    } else {            // vt TILED
        #pragma unroll
        for (int m = 0; m < 2; ++m) {
            const int srow0 = rowBase + m*16 + g4*4;
            const int b = srow0 >> 11, s0 = srow0 & 2047;
            unsigned short* tb = vt + (size_t)(b*H_ + h) * S_ * DK
                               + (s0 >> 6) * 4096 + ((s0 & 63) >> 3) * 512 + (s0 & 7);
            #pragma unroll
            for (int n = 0; n < 4; ++n) {
                const int d = n*16 + l15;
                const float bb = bias[h*64 + d];
                u16x4 pk;
                #pragma unroll
                for (int r = 0; r < 4; ++r) pk[r] = f2bf(acc[m][n][r] + bb);
                *(u16x4*)(tb + d * 8) = pk;
            }
        }
    }
}

// ---------------------------------------------------------------------------
// Split-bf16 MFMA GEMM (pre-split A via gload; output projection). Unchanged.
// ---------------------------------------------------------------------------
__global__ __launch_bounds__(512) void mfma_gemm0(
    const unsigned short* __restrict__ Ah, const unsigned short* __restrict__ Al,
    const unsigned short* __restrict__ Wh, const unsigned short* __restrict__ Wl,
    const float* __restrict__ bias, float* __restrict__ Out)
{
    __shared__ __align__(16) unsigned short lds[2][4][4096];
    const int tid = threadIdx.x;
    const int w = tid >> 6, lane = tid & 63;
    const int l15 = lane & 15, g4 = lane >> 4;
    const int wr = w >> 1, wc = w & 1;
    const int bx = blockIdx.x, by = blockIdx.y;

    const int tileId = w >> 1;
    const int halfT  = w & 1;
    const unsigned short* gsrc = (tileId==0) ? Ah : (tileId==1) ? Al : (tileId==2) ? Wh : Wl;
    const int row0 = (tileId < 2) ? bx * 128 : by * 128;
    const int su_   = (lane & 7) ^ (lane >> 3);
    const int wrow_ = halfT * 64 + ((lane >> 3) << 1) + (su_ >> 2);
    const char* gp0 = (const char*)gsrc + (size_t)(row0 + wrow_) * 2048 + (su_ & 3) * 16;

    f32x4 acc[2][4];
    #pragma unroll
    for (int m = 0; m < 2; ++m)
        #pragma unroll
        for (int n = 0; n < 4; ++n) acc[m][n] = (f32x4){0.f,0.f,0.f,0.f};

    #define STAGE(T, BUF) do {                                              \
        const char* g_ = gp0 + (size_t)(T) * 64;                            \
        unsigned short* lb_ = &lds[BUF][tileId][halfT * 2048];              \
        gload_lds16(g_,          lb_);                                      \
        gload_lds16(g_ + 32768,  lb_ + 512);                                \
        gload_lds16(g_ + 65536,  lb_ + 1024);                               \
        gload_lds16(g_ + 98304,  lb_ + 1536);                               \
    } while (0)

    STAGE(0, 0);
    __syncthreads();

    for (int t = 0; t < 32; ++t) {
        const int cur = t & 1;
        if (t < 31) STAGE(t + 1, cur ^ 1);
        const unsigned short* lA_h = lds[cur][0];
        const unsigned short* lA_l = lds[cur][1];
        const unsigned short* lW_h = lds[cur][2];
        const unsigned short* lW_l = lds[cur][3];
        bf16x8 ah[2], al2[2], wh4[4], wl4[4];
        #pragma unroll
        for (int m = 0; m < 2; ++m) {
            const int off = swz(wr*32 + m*16 + l15, g4);
            ah[m]  = *(const bf16x8*)(lA_h + off);
            al2[m] = *(const bf16x8*)(lA_l + off);
        }
        #pragma unroll
        for (int n = 0; n < 4; ++n) {
            const int off = swz(wc*64 + n*16 + l15, g4);
            wh4[n] = *(const bf16x8*)(lW_h + off);
            wl4[n] = *(const bf16x8*)(lW_l + off);
        }
        #pragma unroll
        for (int m = 0; m < 2; ++m)
            #pragma unroll
            for (int n = 0; n < 4; ++n) {
                acc[m][n] = __builtin_amdgcn_mfma_f32_16x16x32_bf16(ah[m],  wh4[n], acc[m][n], 0,0,0);
                acc[m][n] = __builtin_amdgcn_mfma_f32_16x16x32_bf16(ah[m],  wl4[n], acc[m][n], 0,0,0);
                acc[m][n] = __builtin_amdgcn_mfma_f32_16x16x32_bf16(al2[m], wh4[n], acc[m][n], 0,0,0);
            }
        __syncthreads();
    }
    #undef STAGE

    const int colBase = by*128 + wc*64;
    const int rowBase = bx*128 + wr*32;
    #pragma unroll
    for (int m = 0; m < 2; ++m) {
        const int row = rowBase + m*16 + g4*4;
        #pragma unroll
        for (int n = 0; n < 4; ++n) {
            const int col = colBase + n*16 + l15;
            const float bb = bias[col];
            #pragma unroll
            for (int r = 0; r < 4; ++r)
                Out[(size_t)(row + r) * 1024 + col] = acc[m][n][r] + bb;
        }
    }
}

// ---------------------------------------------------------------------------
// 32x32-MFMA flash attention (unchanged from round 12 — best known).
// ---------------------------------------------------------------------------
__global__ __launch_bounds__(512, 1) void attn_mfma7(
    const unsigned short* __restrict__ Qb, const unsigned short* __restrict__ Kb,
    const unsigned short* __restrict__ Vt,
    unsigned short* __restrict__ Xh, unsigned short* __restrict__ Xl)
{
    __shared__ __align__(16) char lds[65536];
    const unsigned bid = blockIdx.x;             // 256 blocks
    const int xcd = bid & 7, idx = bid >> 3;
    const int bh  = xcd * 4 + (idx >> 3);
    const int qt  = idx & 7;
    const int tid = threadIdx.x;
    const int w = tid >> 6, lane = tid & 63;
    const int l31 = lane & 31, hi = lane >> 5;
    const size_t bhO = (size_t)bh * S_ * DK;
    const int q0 = qt * 256 + w * 32;

    const int u0   = w * 4;
    const int isV  = u0 >> 4;
    const int u15  = u0 & 15;
    const int su0  = u15 >> 3;
    const unsigned short* sb = (isV ? Vt : Kb) + bhO;
    const int ch0 = u15 & 7;
    char* const dbase = lds;

    bf16x8 qf[4];
    #pragma unroll
    for (int ks = 0; ks < 4; ++ks)
        qf[ks] = *(const bf16x8*)(Qb + bhO + (size_t)(q0 + l31) * DK + ks*16 + hi*8);

    f32x16 oT[2];
    #pragma unroll
    for (int dh = 0; dh < 2; ++dh)
        #pragma unroll
        for (int r = 0; r < 16; ++r) oT[dh][r] = 0.f;
    float l_ = 0.f;

    #define ASTAGE(T, BUF) do {                                                     \
        const unsigned short* g_ = sb + (size_t)((T)*2 + su0) * 4096 + ch0 * 512    \
                                   + lane * 8;                                      \
        char* d_ = dbase + (BUF)*32768 + isV*16384 + su0*8192 + ch0*1024 + lane*16; \
        gload_lds16(g_,         d_);                                                \
        gload_lds16(g_ + 512,   d_ + 1024);                                         \
        gload_lds16(g_ + 1024,  d_ + 2048);                                         \
        gload_lds16(g_ + 1536,  d_ + 3072);                                         \
    } while (0)

    ASTAGE(0, 0);
    __syncthreads();

    for (int t = 0; t < 16; ++t) {
        const int cur = t & 1;
        if (t < 15) ASTAGE(t + 1, cur ^ 1);
        const char* Kl = lds + cur * 32768;
        const char* Vl = Kl + 16384;

        f32x16 s2[4];
        __builtin_amdgcn_s_setprio(1);
        #pragma unroll
        for (int kb2 = 0; kb2 < 4; ++kb2) {
            f32x16 a;
            #pragma unroll
            for (int r = 0; r < 16; ++r) a[r] = 0.f;
            const char* kbase = Kl + (kb2 >> 1) * 8192 + ((kb2 & 1) * 32 + l31) * 16;
            #pragma unroll
            for (int ks = 0; ks < 4; ++ks) {
                bf16x8 kf = *(const bf16x8*)(kbase + (ks*2 + hi) * 1024);
                a = __builtin_amdgcn_mfma_f32_32x32x16_bf16(kf, qf[ks], a, 0, 0, 0);
            }
            s2[kb2] = a;
        }
        __builtin_amdgcn_s_setprio(0);

        {
            float lsum = 0.f;
            #pragma unroll
            for (int kb2 = 0; kb2 < 4; ++kb2)
                #pragma unroll
                for (int r = 0; r < 16; ++r) {
                    const float p = EXP2(s2[kb2][r]);
                    s2[kb2][r] = p; lsum += p;
                }
            l_ += lsum;
        }

        // PV: P-frag via cvt_pk + permlane32_swap.
        #pragma unroll
        for (int ks2 = 0; ks2 < 8; ++ks2) {
            const int kb2 = ks2 >> 1;
            const int R0  = (ks2 & 1) * 8;
            unsigned a0 = cvtpk(s2[kb2][R0+0], s2[kb2][R0+1]);
            unsigned a1 = cvtpk(s2[kb2][R0+2], s2[kb2][R0+3]);
            unsigned b0 = cvtpk(s2[kb2][R0+4], s2[kb2][R0+5]);
            unsigned b1 = cvtpk(s2[kb2][R0+6], s2[kb2][R0+7]);
            asm("v_permlane32_swap_b32 %0, %1" : "+v"(a0), "+v"(b0));
            asm("v_permlane32_swap_b32 %0, %1" : "+v"(a1), "+v"(b1));
            union { unsigned u[4]; bf16x8 v; } pf;
            pf.u[0] = a0; pf.u[1] = a1; pf.u[2] = b0; pf.u[3] = b1;
            const char* vbase = Vl + (ks2 >> 2) * 8192 + (((ks2 & 3) * 2) + hi) * 1024;
            __builtin_amdgcn_s_setprio(1);
            #pragma unroll
            for (int dh = 0; dh < 2; ++dh) {
                bf16x8 vf = *(const bf16x8*)(vbase + (dh*32 + l31) * 16);
                oT[dh] = __builtin_amdgcn_mfma_f32_32x32x16_bf16(vf, pf.v, oT[dh], 0, 0, 0);
            }
            __builtin_amdgcn_s_setprio(0);
        }
        __syncthreads();
    }
    #undef ASTAGE

    l_ += __shfl_xor(l_, 32, 64);
    const float inv = 1.0f / l_;
    const int b = bh >> 4, h = bh & 15;
    const int q = q0 + l31;
    unsigned short* xh = Xh + (((size_t)b * S_ + q) * H_ + h) * DK;
    unsigned short* xl = Xl + (((size_t)b * S_ + q) * H_ + h) * DK;
    #pragma unroll
    for (int dh = 0; dh < 2; ++dh)
        #pragma unroll
        for (int tt = 0; tt < 4; ++tt) {
            const int dk0 = dh*32 + tt*8 + hi*4;
            u16x4 hv, lv;
            #pragma unroll
            for (int r = 0; r < 4; ++r) {
                const float o = oT[dh][tt*4 + r] * inv;
                const unsigned short hb = f2bf(o);
                hv[r] = hb;
                lv[r] = f2bf(o - bf2f(hb));
            }
            *(u16x4*)(xh + dk0) = hv;
            *(u16x4*)(xl + dk0) = lv;
        }
}

// ---------------------------------------------------------------------------
extern "C" void kernel_launch(void* const* d_in, const int* in_sizes, int n_in,
                              void* d_out, int out_size, void* d_ws, size_t ws_size,
                              hipStream_t stream)
{
    const float* query = (const float*)d_in[0];
    const float* key   = (const float*)d_in[1];
    const float* value = (const float*)d_in[2];
    const float* Wq = (const float*)d_in[3];  const float* bq = (const float*)d_in[4];
    const float* Wk = (const float*)d_in[5];  const float* bk = (const float*)d_in[6];
    const float* Wv = (const float*)d_in[7];  const float* bv = (const float*)d_in[8];
    const float* Wo = (const float*)d_in[9];  const float* bo = (const float*)d_in[10];
    float* out = (float*)d_out;

    char* ws = (char*)d_ws;
    const size_t MB = (size_t)1 << 20;
    unsigned short* Xh  = (unsigned short*)(ws + 0*MB);
    unsigned short* Xl  = (unsigned short*)(ws + 8*MB);
    unsigned short* qb  = (unsigned short*)(ws + 16*MB);
    unsigned short* vt  = (unsigned short*)(ws + 24*MB);
    unsigned short* kb  = (unsigned short*)(ws + 40*MB);
    unsigned short* wsp = (unsigned short*)(ws + 48*MB);
    unsigned short* Woh = wsp + 6291456;     unsigned short* Wol = wsp + 7340032;

    wsplit4<<<2048, 256, 0, stream>>>(Wq, Wk, Wv, Wo, wsp);

    trigemm<<<dim3(32, 8, 3), 512, 0, stream>>>(query, key, value, wsp,
                                                bq, bk, bv, qb, kb, vt);

    attn_mfma7<<<256, 512, 0, stream>>>(qb, kb, vt, Xh, Xl);

    mfma_gemm0<<<dim3(32, 8), 512, 0, stream>>>(Xh, Xl, Woh, Wol, bo, out);
}